// Round 1
// 9496.587 us; speedup vs baseline: 1.3687x; 1.3687x over previous
//
#include <hip/hip_runtime.h>
#include <hip/hip_bf16.h>
#include <math.h>

#define S_LEN 2048
#define DIM   1024
#define NSTR  4
#define NHEAD 16
#define HDIM  64
#define NCC   24        // 2*N + N*N
#define NEXP  8
#define FF    512
#define VOC   32000
#define EPSV  1e-6f

// MoE plan layout (ints): [0]=ntiles, [16..16+4*80)=tiles(e,row0,rowEnd,_),
// [512..512+4096)=row2tok, [4608..4608+4096)=rowpos
#define PLAN_TILES   16
#define PLAN_R2T     512
#define PLAN_RPOS    4608
#define PLAN_INTS    8704
#define MAX_TILES    80

__device__ __forceinline__ float waveReduceSum(float v) {
  for (int off = 32; off > 0; off >>= 1) v += __shfl_down(v, off, 64);
  return v;
}
__device__ __forceinline__ float waveReduceMax(float v) {
  for (int off = 32; off > 0; off >>= 1) v = fmaxf(v, __shfl_down(v, off, 64));
  return v;
}
__device__ __forceinline__ float siluf(float g) { return g / (1.f + expf(-g)); }

// ---------------------------------------------------------------- embed
__global__ __launch_bounds__(256) void k_embed(const int* __restrict__ ids,
                                               const float* __restrict__ embed,
                                               float* __restrict__ x) {
  int s = blockIdx.x;
  int id = ids[s];
  const float4* er = (const float4*)(embed + (size_t)id * DIM);
  float4* xr = (float4*)(x + (size_t)s * NSTR * DIM);
  for (int i = threadIdx.x; i < DIM / 4; i += 256) {
    float4 v = er[i];
    xr[i] = v; xr[i + 256] = v; xr[i + 512] = v; xr[i + 768] = v;
  }
}

// ------------------------------------------------- hyper-connection weights
template <int NOUT, bool SINK>
__global__ __launch_bounds__(256) void k_hc(const float* __restrict__ x,
                                            const float* __restrict__ W,
                                            const float* __restrict__ b,
                                            float* __restrict__ pre,
                                            float* __restrict__ post,
                                            float* __restrict__ Mout) {
  int s = blockIdx.x;
  int tid = threadIdx.x, lane = tid & 63, wid = tid >> 6;
  __shared__ __align__(16) float xs[NSTR * DIM];
  __shared__ float wred[4];
  __shared__ float wacc[4][NOUT];
  const float4* xr = (const float4*)(x + (size_t)s * NSTR * DIM);
  float ss = 0.f;
  for (int i = tid; i < NSTR * DIM / 4; i += 256) {
    float4 v = xr[i];
    ((float4*)xs)[i] = v;
    ss += v.x * v.x + v.y * v.y + v.z * v.z + v.w * v.w;
  }
  ss = waveReduceSum(ss);
  if (lane == 0) wred[wid] = ss;
  __syncthreads();
  float rstd = rsqrtf((wred[0] + wred[1] + wred[2] + wred[3]) / (float)(NSTR * DIM) + EPSV);
  float acc[NOUT];
#pragma unroll
  for (int j = 0; j < NOUT; j++) acc[j] = 0.f;
  for (int i = tid; i < NSTR * DIM; i += 256) {
    float xv = xs[i] * rstd;
    const float4* wr = (const float4*)(W + (size_t)i * NOUT);
#pragma unroll
    for (int j4 = 0; j4 < NOUT / 4; j4++) {
      float4 w = wr[j4];
      acc[j4 * 4 + 0] += xv * w.x; acc[j4 * 4 + 1] += xv * w.y;
      acc[j4 * 4 + 2] += xv * w.z; acc[j4 * 4 + 3] += xv * w.w;
    }
  }
#pragma unroll
  for (int j = 0; j < NOUT; j++) {
    float v = waveReduceSum(acc[j]);
    if (lane == 0) wacc[wid][j] = v;
  }
  __syncthreads();
  if (tid == 0) {
    float raw[NOUT];
#pragma unroll
    for (int j = 0; j < NOUT; j++)
      raw[j] = wacc[0][j] + wacc[1][j] + wacc[2][j] + wacc[3][j] + b[j];
    for (int n = 0; n < 4; n++) pre[s * 4 + n] = 1.f + tanhf(raw[n]);
    if (SINK) {
      for (int n = 0; n < 4; n++) post[s * 4 + n] = 1.f + tanhf(raw[4 + n]);
      float Mv[16];
      float mx = -1e30f;
      for (int i = 0; i < 16; i++) {
        float lg = raw[8 + i] + ((i % 5) == 0 ? 1.f : 0.f);  // + eye(4)
        Mv[i] = lg; mx = fmaxf(mx, lg);
      }
      for (int i = 0; i < 16; i++) Mv[i] = expf(Mv[i] - mx);
      for (int it = 0; it < 20; it++) {
        for (int n = 0; n < 4; n++) {
          float rs = Mv[n*4] + Mv[n*4+1] + Mv[n*4+2] + Mv[n*4+3] + EPSV;
          Mv[n*4] /= rs; Mv[n*4+1] /= rs; Mv[n*4+2] /= rs; Mv[n*4+3] /= rs;
        }
        for (int m = 0; m < 4; m++) {
          float cs = Mv[m] + Mv[4+m] + Mv[8+m] + Mv[12+m] + EPSV;
          Mv[m] /= cs; Mv[4+m] /= cs; Mv[8+m] /= cs; Mv[12+m] /= cs;
        }
      }
      for (int i = 0; i < 16; i++) Mout[s * 16 + i] = Mv[i];
    }
  }
}

// ------------------------------------------------- collapse + rms + scale
__global__ __launch_bounds__(256) void k_coll(const float* __restrict__ x,
                                              const float* __restrict__ pre,
                                              const float* __restrict__ g,
                                              float* __restrict__ out) {
  int s = blockIdx.x, tid = threadIdx.x, lane = tid & 63, wid = tid >> 6;
  __shared__ float cl[DIM];
  __shared__ float wred[4];
  float p0 = pre[s*4+0], p1 = pre[s*4+1], p2 = pre[s*4+2], p3 = pre[s*4+3];
  const float* xr = x + (size_t)s * NSTR * DIM;
  float ss = 0.f;
  for (int d = tid; d < DIM; d += 256) {
    float c = p0*xr[d] + p1*xr[DIM+d] + p2*xr[2*DIM+d] + p3*xr[3*DIM+d];
    cl[d] = c; ss += c * c;
  }
  ss = waveReduceSum(ss);
  if (lane == 0) wred[wid] = ss;
  __syncthreads();
  float rstd = rsqrtf((wred[0]+wred[1]+wred[2]+wred[3]) / (float)DIM + EPSV);
  for (int d = tid; d < DIM; d += 256)
    out[(size_t)s * DIM + d] = cl[d] * rstd * g[d];
}

// ---------------------------------------------------------------- sgemm
template <int BM, int BN>
__global__ __launch_bounds__(256) void sgemm(const float* __restrict__ A,
                                             const float* __restrict__ B,
                                             float* __restrict__ C,
                                             int M, int Kd, int Nn) {
  const int BK = 16;
  const int TM = BM / 16, TN = BN / 16;
  __shared__ __align__(16) float As[BK][BM + 4];
  __shared__ __align__(16) float Bs[BK][BN + 4];
  int tid = threadIdx.x;
  int bn = blockIdx.x, bm = blockIdx.y;
  int ty = tid >> 4, tx = tid & 15;
  float acc[TM][TN];
#pragma unroll
  for (int i = 0; i < TM; i++)
#pragma unroll
    for (int j = 0; j < TN; j++) acc[i][j] = 0.f;
  const float* Ab = A + (size_t)bm * BM * Kd;
  const float* Bb = B + (size_t)bn * BN;
  for (int k0 = 0; k0 < Kd; k0 += BK) {
    for (int i = tid; i < BM * BK / 4; i += 256) {
      int row = i >> 2, c4 = (i & 3) * 4;
      float4 v = *(const float4*)(Ab + (size_t)row * Kd + k0 + c4);
      As[c4+0][row] = v.x; As[c4+1][row] = v.y; As[c4+2][row] = v.z; As[c4+3][row] = v.w;
    }
    for (int i = tid; i < BK * BN / 4; i += 256) {
      int row = i / (BN / 4), c4 = (i % (BN / 4)) * 4;
      *(float4*)(&Bs[row][c4]) = *(const float4*)(Bb + (size_t)(k0 + row) * Nn + c4);
    }
    __syncthreads();
#pragma unroll
    for (int kk = 0; kk < BK; kk++) {
      float a[TM], b[TN];
#pragma unroll
      for (int i = 0; i < TM; i++) a[i] = As[kk][ty + i * 16];
#pragma unroll
      for (int j = 0; j < TN; j++) b[j] = Bs[kk][tx + j * 16];
#pragma unroll
      for (int i = 0; i < TM; i++)
#pragma unroll
        for (int j = 0; j < TN; j++) acc[i][j] += a[i] * b[j];
    }
    __syncthreads();
  }
  float* Cb = C + (size_t)(bm * BM) * Nn + bn * BN;
#pragma unroll
  for (int i = 0; i < TM; i++)
#pragma unroll
    for (int j = 0; j < TN; j++)
      Cb[(size_t)(ty + i * 16) * Nn + tx + j * 16] = acc[i][j];
}

// ---------------------------------------------------------------- rope
__global__ __launch_bounds__(256) void k_rope(float* __restrict__ Q, float* __restrict__ Kb) {
  int idx = blockIdx.x * 256 + threadIdx.x;   // s*256 + h*16 + j
  int s = idx >> 8;
  int r = idx & 255; int h = r >> 4; int j = r & 15;
  float inv = expf(-logf(10000.f) * (float)j / 16.f);
  float ang = (float)s * inv;
  float c = cosf(ang), sn = sinf(ang);
  size_t base = (size_t)s * DIM + h * HDIM;
  float x1 = Q[base + j], x2 = Q[base + 16 + j];
  Q[base + j] = x1 * c - x2 * sn; Q[base + 16 + j] = x1 * sn + x2 * c;
  x1 = Kb[base + j]; x2 = Kb[base + 16 + j];
  Kb[base + j] = x1 * c - x2 * sn; Kb[base + 16 + j] = x1 * sn + x2 * c;
}

// ---------------------------------------------------------------- attention
__global__ __launch_bounds__(256) void k_attn(const float* __restrict__ Q,
                                              const float* __restrict__ Kb,
                                              const float* __restrict__ V,
                                              float* __restrict__ O) {
  int q = blockIdx.x, h = blockIdx.y, tid = threadIdx.x, lane = tid & 63, wid = tid >> 6;
  __shared__ __align__(16) float qv[HDIM];
  __shared__ float sc[S_LEN];
  __shared__ float wred[4];
  __shared__ float osum[4][HDIM];
  if (tid < HDIM) qv[tid] = Q[(size_t)q * DIM + h * HDIM + tid];
  __syncthreads();
  float mx = -1e30f;
  for (int k = tid; k <= q; k += 256) {
    const float4* kr = (const float4*)(Kb + (size_t)k * DIM + h * HDIM);
    float dt = 0.f;
#pragma unroll
    for (int d4 = 0; d4 < 16; d4++) {
      float4 kv = kr[d4];
      dt += qv[d4*4+0]*kv.x + qv[d4*4+1]*kv.y + qv[d4*4+2]*kv.z + qv[d4*4+3]*kv.w;
    }
    dt *= 0.125f;                 // 1/sqrt(64)
    sc[k] = dt; mx = fmaxf(mx, dt);
  }
  mx = waveReduceMax(mx);
  if (lane == 0) wred[wid] = mx;
  __syncthreads();
  float gm = fmaxf(fmaxf(wred[0], wred[1]), fmaxf(wred[2], wred[3]));
  __syncthreads();
  float ls = 0.f;
  for (int k = tid; k <= q; k += 256) { float e = expf(sc[k] - gm); sc[k] = e; ls += e; }
  ls = waveReduceSum(ls);
  if (lane == 0) wred[wid] = ls;
  __syncthreads();
  float gs = wred[0] + wred[1] + wred[2] + wred[3];
  int d = tid & 63, part = tid >> 6;
  float acc = 0.f;
  for (int k = part; k <= q; k += 4) acc += sc[k] * V[(size_t)k * DIM + h * HDIM + d];
  osum[part][d] = acc;
  __syncthreads();
  if (tid < HDIM)
    O[(size_t)q * DIM + h * HDIM + tid] =
        (osum[0][tid] + osum[1][tid] + osum[2][tid] + osum[3][tid]) / gs;
}

// --------------------------------------------- hyper-connection update
__global__ __launch_bounds__(256) void k_hcupd(const float* __restrict__ x,
                                               const float* __restrict__ a,
                                               const float* __restrict__ a2,
                                               const float* __restrict__ post,
                                               const float* __restrict__ Mb,
                                               float* __restrict__ xo) {
  int s = blockIdx.x, tid = threadIdx.x;
  __shared__ float Ms[16];
  if (tid < 16) Ms[tid] = Mb[s * 16 + tid];
  __syncthreads();
  float p0 = post[s*4+0], p1 = post[s*4+1], p2 = post[s*4+2], p3 = post[s*4+3];
  const float* xr = x + (size_t)s * NSTR * DIM;
  float* xw = xo + (size_t)s * NSTR * DIM;
  for (int d = tid; d < DIM; d += 256) {
    float av = a[(size_t)s * DIM + d];
    if (a2) av += a2[(size_t)s * DIM + d];
    float x0 = xr[d], x1 = xr[DIM+d], x2 = xr[2*DIM+d], x3 = xr[3*DIM+d];
    float o0 = p0*av + Ms[0]*x0 + Ms[4]*x1 + Ms[8]*x2  + Ms[12]*x3;
    float o1 = p1*av + Ms[1]*x0 + Ms[5]*x1 + Ms[9]*x2  + Ms[13]*x3;
    float o2 = p2*av + Ms[2]*x0 + Ms[6]*x1 + Ms[10]*x2 + Ms[14]*x3;
    float o3 = p3*av + Ms[3]*x0 + Ms[7]*x1 + Ms[11]*x2 + Ms[15]*x3;
    xw[d] = o0; xw[DIM+d] = o1; xw[2*DIM+d] = o2; xw[3*DIM+d] = o3;
  }
}

// ---------------------------------------------------------------- gating
__global__ __launch_bounds__(256) void k_gate(const float* __restrict__ hb,
                                              const float* __restrict__ gw,
                                              float* __restrict__ gates) {
  int t = blockIdx.x, tid = threadIdx.x;
  int e = tid >> 5, l32 = tid & 31;
  __shared__ float ge[8];
  const float* xr = hb + (size_t)t * DIM;
  const float* wr = gw + (size_t)e * DIM;
  float a = 0.f;
  for (int d = l32; d < DIM; d += 32) a += xr[d] * wr[d];
  for (int off = 16; off > 0; off >>= 1) a += __shfl_down(a, off, 32);
  if (l32 == 0) ge[e] = a;
  __syncthreads();
  if (tid < 8) {
    float v = ge[tid];
    float sp = fmaxf(v, 0.f) + log1pf(expf(-fabsf(v)));  // softplus, stable
    gates[t * 8 + tid] = sqrtf(sp);
  }
}

__global__ __launch_bounds__(256) void k_route(const float* __restrict__ gates,
                                               const int* __restrict__ ids,
                                               const int* __restrict__ tid2eid,
                                               int is_hash,
                                               int* __restrict__ idxb,
                                               float* __restrict__ wgtb) {
  int t = blockIdx.x * 256 + threadIdx.x;
  if (t >= S_LEN) return;
  int e0, e1;
  if (is_hash) {
    int id = ids[t];
    e0 = tid2eid[id * 2]; e1 = tid2eid[id * 2 + 1];
  } else {
    const float* g = gates + t * 8;
    e0 = 0; float b0 = g[0];
    for (int e = 1; e < 8; e++) if (g[e] > b0) { b0 = g[e]; e0 = e; }
    e1 = (e0 == 0) ? 1 : 0; float b1 = g[e1];
    for (int e = 0; e < 8; e++) {
      if (e == e0) continue;
      if (g[e] > b1) { b1 = g[e]; e1 = e; }
    }
  }
  float w0 = gates[t * 8 + e0], w1 = gates[t * 8 + e1];
  float f = 2.5f / (w0 + w1 + 1e-20f);
  idxb[t * 2] = e0; idxb[t * 2 + 1] = e1;
  wgtb[t * 2] = w0 * f; wgtb[t * 2 + 1] = w1 * f;
}

// --------------------------------------------- MoE plan: group rows by expert
// rows are (token,slot) pairs, rowid = t*2+slot, 4096 total. One block.
__global__ __launch_bounds__(1024) void k_moe_plan(const int* __restrict__ idxb,
                                                   int* __restrict__ plan) {
  __shared__ int scnt[NEXP], soff[NEXP], sfill[NEXP];
  int tid = threadIdx.x;
  if (tid < NEXP) { scnt[tid] = 0; sfill[tid] = 0; }
  __syncthreads();
  for (int r = tid; r < 2 * S_LEN; r += 1024) atomicAdd(&scnt[idxb[r]], 1);
  __syncthreads();
  if (tid == 0) {
    int nt = 0, run = 0;
    for (int e = 0; e < NEXP; e++) {
      soff[e] = run;
      int c = scnt[e];
      for (int t0 = 0; t0 < c; t0 += 64) {
        plan[PLAN_TILES + nt * 4 + 0] = e;
        plan[PLAN_TILES + nt * 4 + 1] = run + t0;   // row0
        plan[PLAN_TILES + nt * 4 + 2] = run + c;    // rowEnd (expert range end)
        nt++;
      }
      run += c;
    }
    plan[0] = nt;
  }
  __syncthreads();
  for (int r = tid; r < 2 * S_LEN; r += 1024) {
    int e = idxb[r];
    int pos = soff[e] + atomicAdd(&sfill[e], 1);
    plan[PLAN_R2T + pos] = r;     // grouped row -> (token,slot)
    plan[PLAN_RPOS + r] = pos;    // (token,slot) -> grouped row
  }
}

// --------------------------------------------- grouped expert g/u GEMM
// act[gr, f] = silu(x_tok @ wg_e)[f] * (x_tok @ wu_e)[f], 64-row tiles per expert
__global__ __launch_bounds__(256) void k_moe_gu(const float* __restrict__ hb,
                                                const int* __restrict__ plan,
                                                const float* __restrict__ wg,
                                                const float* __restrict__ wu,
                                                float* __restrict__ act) {
  int tl = blockIdx.y;
  if (tl >= plan[0]) return;
  const int* td = plan + PLAN_TILES + tl * 4;
  int e = td[0], row0 = td[1], rowEnd = td[2];
  int bn = blockIdx.x;                        // 64-col tile over FF
  const int* r2t = plan + PLAN_R2T;
  __shared__ int toks[64];
  __shared__ __align__(16) float As[16][68];
  __shared__ __align__(16) float Bg[16][68];
  __shared__ __align__(16) float Bu[16][68];
  int tid = threadIdx.x;
  if (tid < 64) {
    int gr = row0 + tid;
    toks[tid] = r2t[min(gr, rowEnd - 1)] >> 1;
  }
  __syncthreads();
  int ty = tid >> 4, tx = tid & 15;
  float accg[4][4], accu[4][4];
#pragma unroll
  for (int i = 0; i < 4; i++)
#pragma unroll
    for (int j = 0; j < 4; j++) { accg[i][j] = 0.f; accu[i][j] = 0.f; }
  const float* wgb = wg + (size_t)e * DIM * FF + bn * 64;
  const float* wub = wu + (size_t)e * DIM * FF + bn * 64;
  int arow = tid >> 2, ac4 = (tid & 3) * 4;   // A: 64 rows x 4 float4
  int brow = tid >> 4, bc4 = (tid & 15) * 4;  // B: 16 rows x 16 float4
  for (int k0 = 0; k0 < DIM; k0 += 16) {
    float4 av = *(const float4*)(hb + (size_t)toks[arow] * DIM + k0 + ac4);
    float4 gv = *(const float4*)(wgb + (size_t)(k0 + brow) * FF + bc4);
    float4 uv = *(const float4*)(wub + (size_t)(k0 + brow) * FF + bc4);
    __syncthreads();
    As[ac4+0][arow] = av.x; As[ac4+1][arow] = av.y;
    As[ac4+2][arow] = av.z; As[ac4+3][arow] = av.w;
    *(float4*)(&Bg[brow][bc4]) = gv;
    *(float4*)(&Bu[brow][bc4]) = uv;
    __syncthreads();
#pragma unroll
    for (int kk = 0; kk < 16; kk++) {
      float a[4], bgv[4], buv[4];
#pragma unroll
      for (int i = 0; i < 4; i++) a[i] = As[kk][ty + i * 16];
#pragma unroll
      for (int j = 0; j < 4; j++) { bgv[j] = Bg[kk][tx + j * 16]; buv[j] = Bu[kk][tx + j * 16]; }
#pragma unroll
      for (int i = 0; i < 4; i++)
#pragma unroll
        for (int j = 0; j < 4; j++) {
          accg[i][j] += a[i] * bgv[j];
          accu[i][j] += a[i] * buv[j];
        }
    }
  }
#pragma unroll
  for (int i = 0; i < 4; i++) {
    int gr = row0 + ty + i * 16;
    if (gr < rowEnd) {
#pragma unroll
      for (int j = 0; j < 4; j++)
        act[(size_t)gr * FF + bn * 64 + tx + j * 16] = siluf(accg[i][j]) * accu[i][j];
    }
  }
}

// --------------------------------------------- grouped expert down GEMM
// rowout[gr, d] = act[gr] @ wd_e[e]
__global__ __launch_bounds__(256) void k_moe_down(const float* __restrict__ act,
                                                  const int* __restrict__ plan,
                                                  const float* __restrict__ wd,
                                                  float* __restrict__ rowout) {
  int tl = blockIdx.y;
  if (tl >= plan[0]) return;
  const int* td = plan + PLAN_TILES + tl * 4;
  int e = td[0], row0 = td[1], rowEnd = td[2];
  int bn = blockIdx.x;                        // 64-col tile over DIM
  __shared__ __align__(16) float As[16][68];
  __shared__ __align__(16) float Bs[16][68];
  int tid = threadIdx.x;
  int ty = tid >> 4, tx = tid & 15;
  float acc[4][4];
#pragma unroll
  for (int i = 0; i < 4; i++)
#pragma unroll
    for (int j = 0; j < 4; j++) acc[i][j] = 0.f;
  const float* wdb = wd + (size_t)e * FF * DIM + bn * 64;
  int arow = tid >> 2, ac4 = (tid & 3) * 4;
  int brow = tid >> 4, bc4 = (tid & 15) * 4;
  int asrc = min(row0 + arow, rowEnd - 1);
  for (int k0 = 0; k0 < FF; k0 += 16) {
    float4 av = *(const float4*)(act + (size_t)asrc * FF + k0 + ac4);
    float4 bv = *(const float4*)(wdb + (size_t)(k0 + brow) * DIM + bc4);
    __syncthreads();
    As[ac4+0][arow] = av.x; As[ac4+1][arow] = av.y;
    As[ac4+2][arow] = av.z; As[ac4+3][arow] = av.w;
    *(float4*)(&Bs[brow][bc4]) = bv;
    __syncthreads();
#pragma unroll
    for (int kk = 0; kk < 16; kk++) {
      float a[4], b[4];
#pragma unroll
      for (int i = 0; i < 4; i++) a[i] = As[kk][ty + i * 16];
#pragma unroll
      for (int j = 0; j < 4; j++) b[j] = Bs[kk][tx + j * 16];
#pragma unroll
      for (int i = 0; i < 4; i++)
#pragma unroll
        for (int j = 0; j < 4; j++) acc[i][j] += a[i] * b[j];
    }
  }
#pragma unroll
  for (int i = 0; i < 4; i++) {
    int gr = row0 + ty + i * 16;
    if (gr < rowEnd) {
#pragma unroll
      for (int j = 0; j < 4; j++)
        rowout[(size_t)gr * DIM + bn * 64 + tx + j * 16] = acc[i][j];
    }
  }
}

// --------------------------------------------- combine the two slots
__global__ __launch_bounds__(256) void k_moe_comb(const float* __restrict__ rowout,
                                                  const int* __restrict__ plan,
                                                  const float* __restrict__ wgtb,
                                                  float* __restrict__ routed) {
  int t = blockIdx.x, tid = threadIdx.x;
  const int* rowpos = plan + PLAN_RPOS;
  int p0 = rowpos[t * 2], p1 = rowpos[t * 2 + 1];
  float w0 = wgtb[t * 2], w1 = wgtb[t * 2 + 1];
  const float4* r0 = (const float4*)(rowout + (size_t)p0 * DIM);
  const float4* r1 = (const float4*)(rowout + (size_t)p1 * DIM);
  float4* o = (float4*)(routed + (size_t)t * DIM);
  float4 a = r0[tid], b = r1[tid], c;
  c.x = w0 * a.x + w1 * b.x; c.y = w0 * a.y + w1 * b.y;
  c.z = w0 * a.z + w1 * b.z; c.w = w0 * a.w + w1 * b.w;
  o[tid] = c;
}

__global__ __launch_bounds__(256) void k_silu_mul(const float* __restrict__ g,
                                                  const float* __restrict__ u,
                                                  float* __restrict__ o, int n) {
  int i = blockIdx.x * 256 + threadIdx.x;
  if (i < n) { float gv = g[i]; o[i] = siluf(gv) * u[i]; }
}

// =======================================================================
extern "C" void kernel_launch(void* const* d_in, const int* in_sizes, int n_in,
                              void* d_out, int out_size, void* d_ws, size_t ws_size,
                              hipStream_t stream) {
  (void)in_sizes; (void)n_in; (void)out_size; (void)ws_size;
  const int*   ids      = (const int*)d_in[0];
  const int*   tid2eid  = (const int*)d_in[1];
  const float* embed    = (const float*)d_in[2];
  const float* attn_hc_w= (const float*)d_in[3];
  const float* attn_hc_b= (const float*)d_in[4];
  const float* ffn_hc_w = (const float*)d_in[5];
  const float* ffn_hc_b = (const float*)d_in[6];
  const float* ln1      = (const float*)d_in[7];
  const float* ln2      = (const float*)d_in[8];
  const float* wq       = (const float*)d_in[9];
  const float* wk       = (const float*)d_in[10];
  const float* wv       = (const float*)d_in[11];
  const float* wo       = (const float*)d_in[12];
  const float* gate_w   = (const float*)d_in[13];
  const float* wg_e     = (const float*)d_in[14];
  const float* wu_e     = (const float*)d_in[15];
  const float* wd_e     = (const float*)d_in[16];
  const float* wg_s     = (const float*)d_in[17];
  const float* wu_s     = (const float*)d_in[18];
  const float* wd_s     = (const float*)d_in[19];
  const float* head_w   = (const float*)d_in[20];
  const float* head_b   = (const float*)d_in[21];
  const float* fnw      = (const float*)d_in[22];
  const float* lm_head  = (const float*)d_in[23];
  float* out = (float*)d_out;

  float* ws = (float*)d_ws;
  size_t o = 0;
  float* X    = ws + o; o += (size_t)S_LEN * NSTR * DIM;   // state, updated in place
  float* HBUF = ws + o; o += (size_t)S_LEN * DIM;
  float* T1   = ws + o; o += (size_t)S_LEN * DIM;          // q / grouped expert act (4096x512)
  float* T2   = ws + o; o += (size_t)S_LEN * DIM;          // k / routed
  float* T3   = ws + o; o += (size_t)S_LEN * DIM;          // v / gs,acts
  float* T4   = ws + o; o += (size_t)S_LEN * DIM;          // o / us,shared
  float* PRE  = ws + o; o += (size_t)S_LEN * 4;
  float* POST = ws + o; o += (size_t)S_LEN * 4;
  float* MM   = ws + o; o += (size_t)S_LEN * 16;
  float* GATES= ws + o; o += (size_t)S_LEN * 8;
  float* WGT  = ws + o; o += (size_t)S_LEN * 2;
  int*   IDX  = (int*)(ws + o); o += (size_t)S_LEN * 2;
  int*   PLAN = (int*)(ws + o); o += (size_t)PLAN_INTS;
  // rowout (4096 x 1024 f32 = 16.8 MB) lives in d_out scratch space; it is
  // fully dead before the final lm_head sgemm overwrites all of d_out.
  float* ROWOUT = out;

  dim3 g128(DIM / 128, S_LEN / 128);
  dim3 gattn(S_LEN, NHEAD);

  k_embed<<<S_LEN, 256, 0, stream>>>(ids, embed, X);

  for (int l = 0; l < 2; l++) {
    // ---- attention sub-block
    k_hc<NCC, true><<<S_LEN, 256, 0, stream>>>(X, attn_hc_w + (size_t)l * NSTR * DIM * NCC,
                                               attn_hc_b + l * NCC, PRE, POST, MM);
    k_coll<<<S_LEN, 256, 0, stream>>>(X, PRE, ln1 + (size_t)l * DIM, HBUF);
    sgemm<128,128><<<g128, 256, 0, stream>>>(HBUF, wq + (size_t)l * DIM * DIM, T1, S_LEN, DIM, DIM);
    sgemm<128,128><<<g128, 256, 0, stream>>>(HBUF, wk + (size_t)l * DIM * DIM, T2, S_LEN, DIM, DIM);
    sgemm<128,128><<<g128, 256, 0, stream>>>(HBUF, wv + (size_t)l * DIM * DIM, T3, S_LEN, DIM, DIM);
    k_rope<<<S_LEN, 256, 0, stream>>>(T1, T2);
    k_attn<<<gattn, 256, 0, stream>>>(T1, T2, T3, T4);
    sgemm<128,128><<<g128, 256, 0, stream>>>(T4, wo + (size_t)l * DIM * DIM, HBUF, S_LEN, DIM, DIM);
    k_hcupd<<<S_LEN, 256, 0, stream>>>(X, HBUF, nullptr, POST, MM, X);

    // ---- MoE sub-block (grouped-by-expert GEMMs)
    k_hc<NCC, true><<<S_LEN, 256, 0, stream>>>(X, ffn_hc_w + (size_t)l * NSTR * DIM * NCC,
                                               ffn_hc_b + l * NCC, PRE, POST, MM);
    k_coll<<<S_LEN, 256, 0, stream>>>(X, PRE, ln2 + (size_t)l * DIM, HBUF);
    k_gate<<<S_LEN, 256, 0, stream>>>(HBUF, gate_w + (size_t)l * NEXP * DIM, GATES);
    k_route<<<S_LEN / 256, 256, 0, stream>>>(GATES, ids, tid2eid, (l == 0) ? 1 : 0, IDX, WGT);
    k_moe_plan<<<1, 1024, 0, stream>>>(IDX, PLAN);
    k_moe_gu<<<dim3(FF / 64, MAX_TILES), 256, 0, stream>>>(HBUF, PLAN,
                                               wg_e + (size_t)l * NEXP * DIM * FF,
                                               wu_e + (size_t)l * NEXP * DIM * FF, T1);
    k_moe_down<<<dim3(DIM / 64, MAX_TILES), 256, 0, stream>>>(T1, PLAN,
                                               wd_e + (size_t)l * NEXP * FF * DIM, ROWOUT);
    k_moe_comb<<<S_LEN, 256, 0, stream>>>(ROWOUT, PLAN, WGT, T2);
    dim3 g64a(FF / 64, S_LEN / 64);
    sgemm<64,64><<<g64a, 256, 0, stream>>>(HBUF, wg_s + (size_t)l * DIM * FF, T3, S_LEN, DIM, FF);
    sgemm<64,64><<<g64a, 256, 0, stream>>>(HBUF, wu_s + (size_t)l * DIM * FF, T4, S_LEN, DIM, FF);
    k_silu_mul<<<(S_LEN * FF) / 256, 256, 0, stream>>>(T3, T4, T3, S_LEN * FF);
    dim3 g64b(DIM / 64, S_LEN / 64);
    sgemm<64,64><<<g64b, 256, 0, stream>>>(T3, wd_s + (size_t)l * FF * DIM, T4, S_LEN, FF, DIM);
    k_hcupd<<<S_LEN, 256, 0, stream>>>(X, T2, T4, POST, MM, X);
  }

  // ---- final head
  k_hc<4, false><<<S_LEN, 256, 0, stream>>>(X, head_w, head_b, PRE, nullptr, nullptr);
  k_coll<<<S_LEN, 256, 0, stream>>>(X, PRE, fnw, HBUF);
  dim3 gout(VOC / 128, S_LEN / 128);
  sgemm<128,128><<<gout, 256, 0, stream>>>(HBUF, lm_head, out, S_LEN, DIM, VOC);
}

// Round 2
// 7590.659 us; speedup vs baseline: 1.7124x; 1.2511x over previous
//
#include <hip/hip_runtime.h>
#include <hip/hip_bf16.h>
#include <math.h>

#define S_LEN 2048
#define DIM   1024
#define NSTR  4
#define NHEAD 16
#define HDIM  64
#define NCC   24        // 2*N + N*N
#define NEXP  8
#define FF    512
#define VOC   32000
#define EPSV  1e-6f

// MoE plan layout (ints): [0]=ntiles, [16..16+4*80)=tiles(e,row0,rowEnd,_),
// [512..512+4096)=row2tok, [4608..4608+4096)=rowpos
#define PLAN_TILES   16
#define PLAN_R2T     512
#define PLAN_RPOS    4608
#define PLAN_INTS    8704
#define MAX_TILES    80

// lm_head bf16 MFMA path: process N in chunks of 6400 cols (50 x 128-tiles)
#define LM_CHUNK  6400

typedef __attribute__((ext_vector_type(8))) short s16x8;
typedef __attribute__((ext_vector_type(4))) float f32x4;

__device__ __forceinline__ float waveReduceSum(float v) {
  for (int off = 32; off > 0; off >>= 1) v += __shfl_down(v, off, 64);
  return v;
}
__device__ __forceinline__ float waveReduceMax(float v) {
  for (int off = 32; off > 0; off >>= 1) v = fmaxf(v, __shfl_down(v, off, 64));
  return v;
}
__device__ __forceinline__ float siluf(float g) { return g / (1.f + expf(-g)); }
__device__ __forceinline__ unsigned short f2bf(float f) {
  union { float f; unsigned int u; } c; c.f = f;
  unsigned int u = c.u;
  return (unsigned short)((u + 0x7fffu + ((u >> 16) & 1u)) >> 16);
}

// ---------------------------------------------------------------- embed
__global__ __launch_bounds__(256) void k_embed(const int* __restrict__ ids,
                                               const float* __restrict__ embed,
                                               float* __restrict__ x) {
  int s = blockIdx.x;
  int id = ids[s];
  const float4* er = (const float4*)(embed + (size_t)id * DIM);
  float4* xr = (float4*)(x + (size_t)s * NSTR * DIM);
  for (int i = threadIdx.x; i < DIM / 4; i += 256) {
    float4 v = er[i];
    xr[i] = v; xr[i + 256] = v; xr[i + 512] = v; xr[i + 768] = v;
  }
}

// ------------------------------------------------- hyper-connection weights
template <int NOUT, bool SINK>
__global__ __launch_bounds__(256) void k_hc(const float* __restrict__ x,
                                            const float* __restrict__ W,
                                            const float* __restrict__ b,
                                            float* __restrict__ pre,
                                            float* __restrict__ post,
                                            float* __restrict__ Mout) {
  int s = blockIdx.x;
  int tid = threadIdx.x, lane = tid & 63, wid = tid >> 6;
  __shared__ __align__(16) float xs[NSTR * DIM];
  __shared__ float wred[4];
  __shared__ float wacc[4][NOUT];
  const float4* xr = (const float4*)(x + (size_t)s * NSTR * DIM);
  float ss = 0.f;
  for (int i = tid; i < NSTR * DIM / 4; i += 256) {
    float4 v = xr[i];
    ((float4*)xs)[i] = v;
    ss += v.x * v.x + v.y * v.y + v.z * v.z + v.w * v.w;
  }
  ss = waveReduceSum(ss);
  if (lane == 0) wred[wid] = ss;
  __syncthreads();
  float rstd = rsqrtf((wred[0] + wred[1] + wred[2] + wred[3]) / (float)(NSTR * DIM) + EPSV);
  float acc[NOUT];
#pragma unroll
  for (int j = 0; j < NOUT; j++) acc[j] = 0.f;
  for (int i = tid; i < NSTR * DIM; i += 256) {
    float xv = xs[i] * rstd;
    const float4* wr = (const float4*)(W + (size_t)i * NOUT);
#pragma unroll
    for (int j4 = 0; j4 < NOUT / 4; j4++) {
      float4 w = wr[j4];
      acc[j4 * 4 + 0] += xv * w.x; acc[j4 * 4 + 1] += xv * w.y;
      acc[j4 * 4 + 2] += xv * w.z; acc[j4 * 4 + 3] += xv * w.w;
    }
  }
#pragma unroll
  for (int j = 0; j < NOUT; j++) {
    float v = waveReduceSum(acc[j]);
    if (lane == 0) wacc[wid][j] = v;
  }
  __syncthreads();
  if (tid == 0) {
    float raw[NOUT];
#pragma unroll
    for (int j = 0; j < NOUT; j++)
      raw[j] = wacc[0][j] + wacc[1][j] + wacc[2][j] + wacc[3][j] + b[j];
    for (int n = 0; n < 4; n++) pre[s * 4 + n] = 1.f + tanhf(raw[n]);
    if (SINK) {
      for (int n = 0; n < 4; n++) post[s * 4 + n] = 1.f + tanhf(raw[4 + n]);
      float Mv[16];
      float mx = -1e30f;
      for (int i = 0; i < 16; i++) {
        float lg = raw[8 + i] + ((i % 5) == 0 ? 1.f : 0.f);  // + eye(4)
        Mv[i] = lg; mx = fmaxf(mx, lg);
      }
      for (int i = 0; i < 16; i++) Mv[i] = expf(Mv[i] - mx);
      for (int it = 0; it < 20; it++) {
        for (int n = 0; n < 4; n++) {
          float rs = Mv[n*4] + Mv[n*4+1] + Mv[n*4+2] + Mv[n*4+3] + EPSV;
          Mv[n*4] /= rs; Mv[n*4+1] /= rs; Mv[n*4+2] /= rs; Mv[n*4+3] /= rs;
        }
        for (int m = 0; m < 4; m++) {
          float cs = Mv[m] + Mv[4+m] + Mv[8+m] + Mv[12+m] + EPSV;
          Mv[m] /= cs; Mv[4+m] /= cs; Mv[8+m] /= cs; Mv[12+m] /= cs;
        }
      }
      for (int i = 0; i < 16; i++) Mout[s * 16 + i] = Mv[i];
    }
  }
}

// ------------------------------------------------- collapse + rms + scale
__global__ __launch_bounds__(256) void k_coll(const float* __restrict__ x,
                                              const float* __restrict__ pre,
                                              const float* __restrict__ g,
                                              float* __restrict__ out) {
  int s = blockIdx.x, tid = threadIdx.x, lane = tid & 63, wid = tid >> 6;
  __shared__ float cl[DIM];
  __shared__ float wred[4];
  float p0 = pre[s*4+0], p1 = pre[s*4+1], p2 = pre[s*4+2], p3 = pre[s*4+3];
  const float* xr = x + (size_t)s * NSTR * DIM;
  float ss = 0.f;
  for (int d = tid; d < DIM; d += 256) {
    float c = p0*xr[d] + p1*xr[DIM+d] + p2*xr[2*DIM+d] + p3*xr[3*DIM+d];
    cl[d] = c; ss += c * c;
  }
  ss = waveReduceSum(ss);
  if (lane == 0) wred[wid] = ss;
  __syncthreads();
  float rstd = rsqrtf((wred[0]+wred[1]+wred[2]+wred[3]) / (float)DIM + EPSV);
  for (int d = tid; d < DIM; d += 256)
    out[(size_t)s * DIM + d] = cl[d] * rstd * g[d];
}

// ---------------------------------------------------------------- sgemm
template <int BM, int BN>
__global__ __launch_bounds__(256) void sgemm(const float* __restrict__ A,
                                             const float* __restrict__ B,
                                             float* __restrict__ C,
                                             int M, int Kd, int Nn) {
  const int BK = 16;
  const int TM = BM / 16, TN = BN / 16;
  __shared__ __align__(16) float As[BK][BM + 4];
  __shared__ __align__(16) float Bs[BK][BN + 4];
  int tid = threadIdx.x;
  int bn = blockIdx.x, bm = blockIdx.y;
  int ty = tid >> 4, tx = tid & 15;
  float acc[TM][TN];
#pragma unroll
  for (int i = 0; i < TM; i++)
#pragma unroll
    for (int j = 0; j < TN; j++) acc[i][j] = 0.f;
  const float* Ab = A + (size_t)bm * BM * Kd;
  const float* Bb = B + (size_t)bn * BN;
  for (int k0 = 0; k0 < Kd; k0 += BK) {
    for (int i = tid; i < BM * BK / 4; i += 256) {
      int row = i >> 2, c4 = (i & 3) * 4;
      float4 v = *(const float4*)(Ab + (size_t)row * Kd + k0 + c4);
      As[c4+0][row] = v.x; As[c4+1][row] = v.y; As[c4+2][row] = v.z; As[c4+3][row] = v.w;
    }
    for (int i = tid; i < BK * BN / 4; i += 256) {
      int row = i / (BN / 4), c4 = (i % (BN / 4)) * 4;
      *(float4*)(&Bs[row][c4]) = *(const float4*)(Bb + (size_t)(k0 + row) * Nn + c4);
    }
    __syncthreads();
#pragma unroll
    for (int kk = 0; kk < BK; kk++) {
      float a[TM], b[TN];
#pragma unroll
      for (int i = 0; i < TM; i++) a[i] = As[kk][ty + i * 16];
#pragma unroll
      for (int j = 0; j < TN; j++) b[j] = Bs[kk][tx + j * 16];
#pragma unroll
      for (int i = 0; i < TM; i++)
#pragma unroll
        for (int j = 0; j < TN; j++) acc[i][j] += a[i] * b[j];
    }
    __syncthreads();
  }
  float* Cb = C + (size_t)(bm * BM) * Nn + bn * BN;
#pragma unroll
  for (int i = 0; i < TM; i++)
#pragma unroll
    for (int j = 0; j < TN; j++)
      Cb[(size_t)(ty + i * 16) * Nn + tx + j * 16] = acc[i][j];
}

// ---------------------------------------------------------------- rope
__global__ __launch_bounds__(256) void k_rope(float* __restrict__ Q, float* __restrict__ Kb) {
  int idx = blockIdx.x * 256 + threadIdx.x;   // s*256 + h*16 + j
  int s = idx >> 8;
  int r = idx & 255; int h = r >> 4; int j = r & 15;
  float inv = expf(-logf(10000.f) * (float)j / 16.f);
  float ang = (float)s * inv;
  float c = cosf(ang), sn = sinf(ang);
  size_t base = (size_t)s * DIM + h * HDIM;
  float x1 = Q[base + j], x2 = Q[base + 16 + j];
  Q[base + j] = x1 * c - x2 * sn; Q[base + 16 + j] = x1 * sn + x2 * c;
  x1 = Kb[base + j]; x2 = Kb[base + 16 + j];
  Kb[base + j] = x1 * c - x2 * sn; Kb[base + 16 + j] = x1 * sn + x2 * c;
}

// ---------------------------------------------------------------- attention
__global__ __launch_bounds__(256) void k_attn(const float* __restrict__ Q,
                                              const float* __restrict__ Kb,
                                              const float* __restrict__ V,
                                              float* __restrict__ O) {
  int q = blockIdx.x, h = blockIdx.y, tid = threadIdx.x, lane = tid & 63, wid = tid >> 6;
  __shared__ __align__(16) float qv[HDIM];
  __shared__ float sc[S_LEN];
  __shared__ float wred[4];
  __shared__ float osum[4][HDIM];
  if (tid < HDIM) qv[tid] = Q[(size_t)q * DIM + h * HDIM + tid];
  __syncthreads();
  float mx = -1e30f;
  for (int k = tid; k <= q; k += 256) {
    const float4* kr = (const float4*)(Kb + (size_t)k * DIM + h * HDIM);
    float dt = 0.f;
#pragma unroll
    for (int d4 = 0; d4 < 16; d4++) {
      float4 kv = kr[d4];
      dt += qv[d4*4+0]*kv.x + qv[d4*4+1]*kv.y + qv[d4*4+2]*kv.z + qv[d4*4+3]*kv.w;
    }
    dt *= 0.125f;                 // 1/sqrt(64)
    sc[k] = dt; mx = fmaxf(mx, dt);
  }
  mx = waveReduceMax(mx);
  if (lane == 0) wred[wid] = mx;
  __syncthreads();
  float gm = fmaxf(fmaxf(wred[0], wred[1]), fmaxf(wred[2], wred[3]));
  __syncthreads();
  float ls = 0.f;
  for (int k = tid; k <= q; k += 256) { float e = expf(sc[k] - gm); sc[k] = e; ls += e; }
  ls = waveReduceSum(ls);
  if (lane == 0) wred[wid] = ls;
  __syncthreads();
  float gs = wred[0] + wred[1] + wred[2] + wred[3];
  int d = tid & 63, part = tid >> 6;
  float acc = 0.f;
  for (int k = part; k <= q; k += 4) acc += sc[k] * V[(size_t)k * DIM + h * HDIM + d];
  osum[part][d] = acc;
  __syncthreads();
  if (tid < HDIM)
    O[(size_t)q * DIM + h * HDIM + tid] =
        (osum[0][tid] + osum[1][tid] + osum[2][tid] + osum[3][tid]) / gs;
}

// --------------------------------------------- hyper-connection update
__global__ __launch_bounds__(256) void k_hcupd(const float* __restrict__ x,
                                               const float* __restrict__ a,
                                               const float* __restrict__ a2,
                                               const float* __restrict__ post,
                                               const float* __restrict__ Mb,
                                               float* __restrict__ xo) {
  int s = blockIdx.x, tid = threadIdx.x;
  __shared__ float Ms[16];
  if (tid < 16) Ms[tid] = Mb[s * 16 + tid];
  __syncthreads();
  float p0 = post[s*4+0], p1 = post[s*4+1], p2 = post[s*4+2], p3 = post[s*4+3];
  const float* xr = x + (size_t)s * NSTR * DIM;
  float* xw = xo + (size_t)s * NSTR * DIM;
  for (int d = tid; d < DIM; d += 256) {
    float av = a[(size_t)s * DIM + d];
    if (a2) av += a2[(size_t)s * DIM + d];
    float x0 = xr[d], x1 = xr[DIM+d], x2 = xr[2*DIM+d], x3 = xr[3*DIM+d];
    float o0 = p0*av + Ms[0]*x0 + Ms[4]*x1 + Ms[8]*x2  + Ms[12]*x3;
    float o1 = p1*av + Ms[1]*x0 + Ms[5]*x1 + Ms[9]*x2  + Ms[13]*x3;
    float o2 = p2*av + Ms[2]*x0 + Ms[6]*x1 + Ms[10]*x2 + Ms[14]*x3;
    float o3 = p3*av + Ms[3]*x0 + Ms[7]*x1 + Ms[11]*x2 + Ms[15]*x3;
    xw[d] = o0; xw[DIM+d] = o1; xw[2*DIM+d] = o2; xw[3*DIM+d] = o3;
  }
}

// ---------------------------------------------------------------- gating
__global__ __launch_bounds__(256) void k_gate(const float* __restrict__ hb,
                                              const float* __restrict__ gw,
                                              float* __restrict__ gates) {
  int t = blockIdx.x, tid = threadIdx.x;
  int e = tid >> 5, l32 = tid & 31;
  __shared__ float ge[8];
  const float* xr = hb + (size_t)t * DIM;
  const float* wr = gw + (size_t)e * DIM;
  float a = 0.f;
  for (int d = l32; d < DIM; d += 32) a += xr[d] * wr[d];
  for (int off = 16; off > 0; off >>= 1) a += __shfl_down(a, off, 32);
  if (l32 == 0) ge[e] = a;
  __syncthreads();
  if (tid < 8) {
    float v = ge[tid];
    float sp = fmaxf(v, 0.f) + log1pf(expf(-fabsf(v)));  // softplus, stable
    gates[t * 8 + tid] = sqrtf(sp);
  }
}

__global__ __launch_bounds__(256) void k_route(const float* __restrict__ gates,
                                               const int* __restrict__ ids,
                                               const int* __restrict__ tid2eid,
                                               int is_hash,
                                               int* __restrict__ idxb,
                                               float* __restrict__ wgtb) {
  int t = blockIdx.x * 256 + threadIdx.x;
  if (t >= S_LEN) return;
  int e0, e1;
  if (is_hash) {
    int id = ids[t];
    e0 = tid2eid[id * 2]; e1 = tid2eid[id * 2 + 1];
  } else {
    const float* g = gates + t * 8;
    e0 = 0; float b0 = g[0];
    for (int e = 1; e < 8; e++) if (g[e] > b0) { b0 = g[e]; e0 = e; }
    e1 = (e0 == 0) ? 1 : 0; float b1 = g[e1];
    for (int e = 0; e < 8; e++) {
      if (e == e0) continue;
      if (g[e] > b1) { b1 = g[e]; e1 = e; }
    }
  }
  float w0 = gates[t * 8 + e0], w1 = gates[t * 8 + e1];
  float f = 2.5f / (w0 + w1 + 1e-20f);
  idxb[t * 2] = e0; idxb[t * 2 + 1] = e1;
  wgtb[t * 2] = w0 * f; wgtb[t * 2 + 1] = w1 * f;
}

// --------------------------------------------- MoE plan: group rows by expert
__global__ __launch_bounds__(1024) void k_moe_plan(const int* __restrict__ idxb,
                                                   int* __restrict__ plan) {
  __shared__ int scnt[NEXP], soff[NEXP], sfill[NEXP];
  int tid = threadIdx.x;
  if (tid < NEXP) { scnt[tid] = 0; sfill[tid] = 0; }
  __syncthreads();
  for (int r = tid; r < 2 * S_LEN; r += 1024) atomicAdd(&scnt[idxb[r]], 1);
  __syncthreads();
  if (tid == 0) {
    int nt = 0, run = 0;
    for (int e = 0; e < NEXP; e++) {
      soff[e] = run;
      int c = scnt[e];
      for (int t0 = 0; t0 < c; t0 += 64) {
        plan[PLAN_TILES + nt * 4 + 0] = e;
        plan[PLAN_TILES + nt * 4 + 1] = run + t0;   // row0
        plan[PLAN_TILES + nt * 4 + 2] = run + c;    // rowEnd (expert range end)
        nt++;
      }
      run += c;
    }
    plan[0] = nt;
  }
  __syncthreads();
  for (int r = tid; r < 2 * S_LEN; r += 1024) {
    int e = idxb[r];
    int pos = soff[e] + atomicAdd(&sfill[e], 1);
    plan[PLAN_R2T + pos] = r;     // grouped row -> (token,slot)
    plan[PLAN_RPOS + r] = pos;    // (token,slot) -> grouped row
  }
}

// --------------------------------------------- grouped expert g/u GEMM
__global__ __launch_bounds__(256) void k_moe_gu(const float* __restrict__ hb,
                                                const int* __restrict__ plan,
                                                const float* __restrict__ wg,
                                                const float* __restrict__ wu,
                                                float* __restrict__ act) {
  int tl = blockIdx.y;
  if (tl >= plan[0]) return;
  const int* td = plan + PLAN_TILES + tl * 4;
  int e = td[0], row0 = td[1], rowEnd = td[2];
  int bn = blockIdx.x;                        // 64-col tile over FF
  const int* r2t = plan + PLAN_R2T;
  __shared__ int toks[64];
  __shared__ __align__(16) float As[16][68];
  __shared__ __align__(16) float Bg[16][68];
  __shared__ __align__(16) float Bu[16][68];
  int tid = threadIdx.x;
  if (tid < 64) {
    int gr = row0 + tid;
    toks[tid] = r2t[min(gr, rowEnd - 1)] >> 1;
  }
  __syncthreads();
  int ty = tid >> 4, tx = tid & 15;
  float accg[4][4], accu[4][4];
#pragma unroll
  for (int i = 0; i < 4; i++)
#pragma unroll
    for (int j = 0; j < 4; j++) { accg[i][j] = 0.f; accu[i][j] = 0.f; }
  const float* wgb = wg + (size_t)e * DIM * FF + bn * 64;
  const float* wub = wu + (size_t)e * DIM * FF + bn * 64;
  int arow = tid >> 2, ac4 = (tid & 3) * 4;   // A: 64 rows x 4 float4
  int brow = tid >> 4, bc4 = (tid & 15) * 4;  // B: 16 rows x 16 float4
  for (int k0 = 0; k0 < DIM; k0 += 16) {
    float4 av = *(const float4*)(hb + (size_t)toks[arow] * DIM + k0 + ac4);
    float4 gv = *(const float4*)(wgb + (size_t)(k0 + brow) * FF + bc4);
    float4 uv = *(const float4*)(wub + (size_t)(k0 + brow) * FF + bc4);
    __syncthreads();
    As[ac4+0][arow] = av.x; As[ac4+1][arow] = av.y;
    As[ac4+2][arow] = av.z; As[ac4+3][arow] = av.w;
    *(float4*)(&Bg[brow][bc4]) = gv;
    *(float4*)(&Bu[brow][bc4]) = uv;
    __syncthreads();
#pragma unroll
    for (int kk = 0; kk < 16; kk++) {
      float a[4], bgv[4], buv[4];
#pragma unroll
      for (int i = 0; i < 4; i++) a[i] = As[kk][ty + i * 16];
#pragma unroll
      for (int j = 0; j < 4; j++) { bgv[j] = Bg[kk][tx + j * 16]; buv[j] = Bu[kk][tx + j * 16]; }
#pragma unroll
      for (int i = 0; i < 4; i++)
#pragma unroll
        for (int j = 0; j < 4; j++) {
          accg[i][j] += a[i] * bgv[j];
          accu[i][j] += a[i] * buv[j];
        }
    }
  }
#pragma unroll
  for (int i = 0; i < 4; i++) {
    int gr = row0 + ty + i * 16;
    if (gr < rowEnd) {
#pragma unroll
      for (int j = 0; j < 4; j++)
        act[(size_t)gr * FF + bn * 64 + tx + j * 16] = siluf(accg[i][j]) * accu[i][j];
    }
  }
}

// --------------------------------------------- grouped expert down GEMM
__global__ __launch_bounds__(256) void k_moe_down(const float* __restrict__ act,
                                                  const int* __restrict__ plan,
                                                  const float* __restrict__ wd,
                                                  float* __restrict__ rowout) {
  int tl = blockIdx.y;
  if (tl >= plan[0]) return;
  const int* td = plan + PLAN_TILES + tl * 4;
  int e = td[0], row0 = td[1], rowEnd = td[2];
  int bn = blockIdx.x;                        // 64-col tile over DIM
  __shared__ __align__(16) float As[16][68];
  __shared__ __align__(16) float Bs[16][68];
  int tid = threadIdx.x;
  int ty = tid >> 4, tx = tid & 15;
  float acc[4][4];
#pragma unroll
  for (int i = 0; i < 4; i++)
#pragma unroll
    for (int j = 0; j < 4; j++) acc[i][j] = 0.f;
  const float* wdb = wd + (size_t)e * FF * DIM + bn * 64;
  int arow = tid >> 2, ac4 = (tid & 3) * 4;
  int brow = tid >> 4, bc4 = (tid & 15) * 4;
  int asrc = min(row0 + arow, rowEnd - 1);
  for (int k0 = 0; k0 < FF; k0 += 16) {
    float4 av = *(const float4*)(act + (size_t)asrc * FF + k0 + ac4);
    float4 bv = *(const float4*)(wdb + (size_t)(k0 + brow) * DIM + bc4);
    __syncthreads();
    As[ac4+0][arow] = av.x; As[ac4+1][arow] = av.y;
    As[ac4+2][arow] = av.z; As[ac4+3][arow] = av.w;
    *(float4*)(&Bs[brow][bc4]) = bv;
    __syncthreads();
#pragma unroll
    for (int kk = 0; kk < 16; kk++) {
      float a[4], b[4];
#pragma unroll
      for (int i = 0; i < 4; i++) a[i] = As[kk][ty + i * 16];
#pragma unroll
      for (int j = 0; j < 4; j++) b[j] = Bs[kk][tx + j * 16];
#pragma unroll
      for (int i = 0; i < 4; i++)
#pragma unroll
        for (int j = 0; j < 4; j++) acc[i][j] += a[i] * b[j];
    }
  }
#pragma unroll
  for (int i = 0; i < 4; i++) {
    int gr = row0 + ty + i * 16;
    if (gr < rowEnd) {
#pragma unroll
      for (int j = 0; j < 4; j++)
        rowout[(size_t)gr * DIM + bn * 64 + tx + j * 16] = acc[i][j];
    }
  }
}

// --------------------------------------------- combine the two slots
__global__ __launch_bounds__(256) void k_moe_comb(const float* __restrict__ rowout,
                                                  const int* __restrict__ plan,
                                                  const float* __restrict__ wgtb,
                                                  float* __restrict__ routed) {
  int t = blockIdx.x, tid = threadIdx.x;
  const int* rowpos = plan + PLAN_RPOS;
  int p0 = rowpos[t * 2], p1 = rowpos[t * 2 + 1];
  float w0 = wgtb[t * 2], w1 = wgtb[t * 2 + 1];
  const float4* r0 = (const float4*)(rowout + (size_t)p0 * DIM);
  const float4* r1 = (const float4*)(rowout + (size_t)p1 * DIM);
  float4* o = (float4*)(routed + (size_t)t * DIM);
  float4 a = r0[tid], b = r1[tid], c;
  c.x = w0 * a.x + w1 * b.x; c.y = w0 * a.y + w1 * b.y;
  c.z = w0 * a.z + w1 * b.z; c.w = w0 * a.w + w1 * b.w;
  o[tid] = c;
}

__global__ __launch_bounds__(256) void k_silu_mul(const float* __restrict__ g,
                                                  const float* __restrict__ u,
                                                  float* __restrict__ o, int n) {
  int i = blockIdx.x * 256 + threadIdx.x;
  if (i < n) { float gv = g[i]; o[i] = siluf(gv) * u[i]; }
}

// --------------------------------------------- lm_head bf16 MFMA path
// cast A (2048x1024 f32) -> bf16
__global__ __launch_bounds__(256) void k_castA(const float* __restrict__ in,
                                               short* __restrict__ out) {
  int i = blockIdx.x * 256 + threadIdx.x;     // over 2M/4
  float4 v = ((const float4*)in)[i];
  short4 o;
  o.x = (short)f2bf(v.x); o.y = (short)f2bf(v.y);
  o.z = (short)f2bf(v.z); o.w = (short)f2bf(v.w);
  ((short4*)out)[i] = o;
}

// transpose-cast chunk of lm_head: B f32 [1024][32000] cols [c0,c0+LM_CHUNK)
// -> BT bf16 [LM_CHUNK][1024]
__global__ __launch_bounds__(256) void k_castT(const float* __restrict__ B,
                                               short* __restrict__ BT, int c0) {
  __shared__ short tile[32][34];
  int bx = blockIdx.x, by = blockIdx.y;       // n-tile (chunk-local), k-tile
  int t = threadIdx.x;
  int n0 = c0 + bx * 32, k0 = by * 32;
  int r = t >> 3, nq = (t & 7) * 4;
  float4 v = *(const float4*)(B + (size_t)(k0 + r) * VOC + n0 + nq);
  tile[nq + 0][r] = (short)f2bf(v.x);
  tile[nq + 1][r] = (short)f2bf(v.y);
  tile[nq + 2][r] = (short)f2bf(v.z);
  tile[nq + 3][r] = (short)f2bf(v.w);
  __syncthreads();
  int n = t >> 3, kq = (t & 7) * 4;
  short4 o;
  o.x = tile[n][kq + 0]; o.y = tile[n][kq + 1];
  o.z = tile[n][kq + 2]; o.w = tile[n][kq + 3];
  *(short4*)(BT + (size_t)(bx * 32 + n) * 1024 + k0 + kq) = o;
}

// C[M, c0..c0+LM_CHUNK) = A(bf16 [2048][1024]) @ BT(bf16 [LM_CHUNK][1024])^T
// 128x128 tile, 4 waves each computing 64x64 via 4x4 mfma_f32_16x16x32_bf16
__global__ __launch_bounds__(256) void k_lmgemm(const short* __restrict__ A,
                                                const short* __restrict__ BT,
                                                float* __restrict__ C, int c0) {
  __shared__ __align__(16) short As[128 * 40];  // row stride 40 shorts = 80B
  __shared__ __align__(16) short Bs[128 * 40];
  int t = threadIdx.x;
  int bn = blockIdx.x, bm = blockIdx.y;
  int w = t >> 6, l = t & 63;
  int wr = w >> 1, wc = w & 1;
  f32x4 acc[4][4];
#pragma unroll
  for (int i = 0; i < 4; i++)
#pragma unroll
    for (int j = 0; j < 4; j++) acc[i][j] = (f32x4){0.f, 0.f, 0.f, 0.f};
  int srow = t >> 1, sseg = t & 1;
  const short* Ag = A + (size_t)(bm * 128 + srow) * 1024 + sseg * 16;
  const short* Bg = BT + (size_t)(bn * 128 + srow) * 1024 + sseg * 16;
  short* Asw = As + srow * 40 + sseg * 16;
  short* Bsw = Bs + srow * 40 + sseg * 16;
  const short* Ar = As + (wr * 64 + (l & 15)) * 40 + (l >> 4) * 8;
  const short* Br = Bs + (wc * 64 + (l & 15)) * 40 + (l >> 4) * 8;
  for (int k0 = 0; k0 < 1024; k0 += 32) {
    s16x8 a0 = *(const s16x8*)(Ag + k0);
    s16x8 a1 = *(const s16x8*)(Ag + k0 + 8);
    s16x8 b0 = *(const s16x8*)(Bg + k0);
    s16x8 b1 = *(const s16x8*)(Bg + k0 + 8);
    __syncthreads();
    *(s16x8*)(Asw) = a0; *(s16x8*)(Asw + 8) = a1;
    *(s16x8*)(Bsw) = b0; *(s16x8*)(Bsw + 8) = b1;
    __syncthreads();
    s16x8 af[4], bf[4];
#pragma unroll
    for (int i = 0; i < 4; i++) af[i] = *(const s16x8*)(Ar + i * 640);
#pragma unroll
    for (int j = 0; j < 4; j++) bf[j] = *(const s16x8*)(Br + j * 640);
#pragma unroll
    for (int i = 0; i < 4; i++)
#pragma unroll
      for (int j = 0; j < 4; j++)
        acc[i][j] = __builtin_amdgcn_mfma_f32_16x16x32_bf16(af[i], bf[j], acc[i][j], 0, 0, 0);
  }
  int rq = (l >> 4) * 4, cn = l & 15;
#pragma unroll
  for (int i = 0; i < 4; i++)
#pragma unroll
    for (int j = 0; j < 4; j++) {
      float* Cp = C + (size_t)(bm * 128 + wr * 64 + i * 16 + rq) * VOC
                  + c0 + bn * 128 + wc * 64 + j * 16 + cn;
#pragma unroll
      for (int r = 0; r < 4; r++) Cp[(size_t)r * VOC] = acc[i][j][r];
    }
}

// =======================================================================
extern "C" void kernel_launch(void* const* d_in, const int* in_sizes, int n_in,
                              void* d_out, int out_size, void* d_ws, size_t ws_size,
                              hipStream_t stream) {
  (void)in_sizes; (void)n_in; (void)out_size; (void)ws_size;
  const int*   ids      = (const int*)d_in[0];
  const int*   tid2eid  = (const int*)d_in[1];
  const float* embed    = (const float*)d_in[2];
  const float* attn_hc_w= (const float*)d_in[3];
  const float* attn_hc_b= (const float*)d_in[4];
  const float* ffn_hc_w = (const float*)d_in[5];
  const float* ffn_hc_b = (const float*)d_in[6];
  const float* ln1      = (const float*)d_in[7];
  const float* ln2      = (const float*)d_in[8];
  const float* wq       = (const float*)d_in[9];
  const float* wk       = (const float*)d_in[10];
  const float* wv       = (const float*)d_in[11];
  const float* wo       = (const float*)d_in[12];
  const float* gate_w   = (const float*)d_in[13];
  const float* wg_e     = (const float*)d_in[14];
  const float* wu_e     = (const float*)d_in[15];
  const float* wd_e     = (const float*)d_in[16];
  const float* wg_s     = (const float*)d_in[17];
  const float* wu_s     = (const float*)d_in[18];
  const float* wd_s     = (const float*)d_in[19];
  const float* head_w   = (const float*)d_in[20];
  const float* head_b   = (const float*)d_in[21];
  const float* fnw      = (const float*)d_in[22];
  const float* lm_head  = (const float*)d_in[23];
  float* out = (float*)d_out;

  float* ws = (float*)d_ws;
  size_t o = 0;
  float* X    = ws + o; o += (size_t)S_LEN * NSTR * DIM;   // state, updated in place
  float* HBUF = ws + o; o += (size_t)S_LEN * DIM;
  float* T1   = ws + o; o += (size_t)S_LEN * DIM;          // q / expert act / ABF16
  float* T2   = ws + o; o += (size_t)S_LEN * DIM;          // k / routed / BT16 lo
  float* T3   = ws + o; o += (size_t)S_LEN * DIM;          // v / gs,acts / BT16 hi
  float* T4   = ws + o; o += (size_t)S_LEN * DIM;          // o / us,shared
  float* PRE  = ws + o; o += (size_t)S_LEN * 4;
  float* POST = ws + o; o += (size_t)S_LEN * 4;
  float* MM   = ws + o; o += (size_t)S_LEN * 16;
  float* GATES= ws + o; o += (size_t)S_LEN * 8;
  float* WGT  = ws + o; o += (size_t)S_LEN * 2;
  int*   IDX  = (int*)(ws + o); o += (size_t)S_LEN * 2;
  int*   PLAN = (int*)(ws + o); o += (size_t)PLAN_INTS;
  // rowout (4096 x 1024 f32 = 16.8 MB) lives in d_out scratch space; it is
  // fully dead before the final lm_head GEMM overwrites all of d_out.
  float* ROWOUT = out;
  // final-head scratch (T1..T4 are dead by then):
  short* ABF16 = (short*)T1;                  // 2048x1024 bf16 = 4 MB (T1 = 8 MB)
  short* BT16  = (short*)T2;                  // LM_CHUNK x 1024 bf16 = 13.1 MB (T2+T3 = 16.8 MB)

  dim3 g128(DIM / 128, S_LEN / 128);
  dim3 gattn(S_LEN, NHEAD);

  k_embed<<<S_LEN, 256, 0, stream>>>(ids, embed, X);

  for (int l = 0; l < 2; l++) {
    // ---- attention sub-block
    k_hc<NCC, true><<<S_LEN, 256, 0, stream>>>(X, attn_hc_w + (size_t)l * NSTR * DIM * NCC,
                                               attn_hc_b + l * NCC, PRE, POST, MM);
    k_coll<<<S_LEN, 256, 0, stream>>>(X, PRE, ln1 + (size_t)l * DIM, HBUF);
    sgemm<128,128><<<g128, 256, 0, stream>>>(HBUF, wq + (size_t)l * DIM * DIM, T1, S_LEN, DIM, DIM);
    sgemm<128,128><<<g128, 256, 0, stream>>>(HBUF, wk + (size_t)l * DIM * DIM, T2, S_LEN, DIM, DIM);
    sgemm<128,128><<<g128, 256, 0, stream>>>(HBUF, wv + (size_t)l * DIM * DIM, T3, S_LEN, DIM, DIM);
    k_rope<<<S_LEN, 256, 0, stream>>>(T1, T2);
    k_attn<<<gattn, 256, 0, stream>>>(T1, T2, T3, T4);
    sgemm<128,128><<<g128, 256, 0, stream>>>(T4, wo + (size_t)l * DIM * DIM, HBUF, S_LEN, DIM, DIM);
    k_hcupd<<<S_LEN, 256, 0, stream>>>(X, HBUF, nullptr, POST, MM, X);

    // ---- MoE sub-block (grouped-by-expert GEMMs)
    k_hc<NCC, true><<<S_LEN, 256, 0, stream>>>(X, ffn_hc_w + (size_t)l * NSTR * DIM * NCC,
                                               ffn_hc_b + l * NCC, PRE, POST, MM);
    k_coll<<<S_LEN, 256, 0, stream>>>(X, PRE, ln2 + (size_t)l * DIM, HBUF);
    k_gate<<<S_LEN, 256, 0, stream>>>(HBUF, gate_w + (size_t)l * NEXP * DIM, GATES);
    k_route<<<S_LEN / 256, 256, 0, stream>>>(GATES, ids, tid2eid, (l == 0) ? 1 : 0, IDX, WGT);
    k_moe_plan<<<1, 1024, 0, stream>>>(IDX, PLAN);
    k_moe_gu<<<dim3(FF / 64, MAX_TILES), 256, 0, stream>>>(HBUF, PLAN,
                                               wg_e + (size_t)l * NEXP * DIM * FF,
                                               wu_e + (size_t)l * NEXP * DIM * FF, T1);
    k_moe_down<<<dim3(DIM / 64, MAX_TILES), 256, 0, stream>>>(T1, PLAN,
                                               wd_e + (size_t)l * NEXP * FF * DIM, ROWOUT);
    k_moe_comb<<<S_LEN, 256, 0, stream>>>(ROWOUT, PLAN, WGT, T2);
    dim3 g64a(FF / 64, S_LEN / 64);
    sgemm<64,64><<<g64a, 256, 0, stream>>>(HBUF, wg_s + (size_t)l * DIM * FF, T3, S_LEN, DIM, FF);
    sgemm<64,64><<<g64a, 256, 0, stream>>>(HBUF, wu_s + (size_t)l * DIM * FF, T4, S_LEN, DIM, FF);
    k_silu_mul<<<(S_LEN * FF) / 256, 256, 0, stream>>>(T3, T4, T3, S_LEN * FF);
    dim3 g64b(DIM / 64, S_LEN / 64);
    sgemm<64,64><<<g64b, 256, 0, stream>>>(T3, wd_s + (size_t)l * FF * DIM, T4, S_LEN, FF, DIM);
    k_hcupd<<<S_LEN, 256, 0, stream>>>(X, T2, T4, POST, MM, X);
  }

  // ---- final head (bf16 MFMA lm_head)
  k_hc<4, false><<<S_LEN, 256, 0, stream>>>(X, head_w, head_b, PRE, nullptr, nullptr);
  k_coll<<<S_LEN, 256, 0, stream>>>(X, PRE, fnw, HBUF);
  k_castA<<<(S_LEN * DIM / 4) / 256, 256, 0, stream>>>(HBUF, ABF16);
  for (int c = 0; c < VOC / LM_CHUNK; c++) {
    k_castT<<<dim3(LM_CHUNK / 32, DIM / 32), 256, 0, stream>>>(lm_head, BT16, c * LM_CHUNK);
    k_lmgemm<<<dim3(LM_CHUNK / 128, S_LEN / 128), 256, 0, stream>>>(ABF16, BT16, out, c * LM_CHUNK);
  }
}

// Round 3
// 4736.736 us; speedup vs baseline: 2.7441x; 1.6025x over previous
//
#include <hip/hip_runtime.h>
#include <hip/hip_bf16.h>
#include <math.h>

#define S_LEN 2048
#define DIM   1024
#define NSTR  4
#define NHEAD 16
#define HDIM  64
#define NCC   24        // 2*N + N*N
#define NEXP  8
#define FF    512
#define VOC   32000
#define EPSV  1e-6f

// MoE plan layout (ints): [0]=ntiles, [16..16+4*80)=tiles(e,row0,rowEnd,_),
// [512..512+4096)=row2tok, [4608..4608+4096)=rowpos
#define PLAN_TILES   16
#define PLAN_R2T     512
#define PLAN_RPOS    4608
#define PLAN_INTS    8704
#define MAX_TILES    80

// lm_head bf16 MFMA path: process N in chunks of 6400 cols (50 x 128-tiles)
#define LM_CHUNK  6400

typedef __attribute__((ext_vector_type(8))) short s16x8;
typedef __attribute__((ext_vector_type(4))) float f32x4;

__device__ __forceinline__ float waveReduceSum(float v) {
  for (int off = 32; off > 0; off >>= 1) v += __shfl_down(v, off, 64);
  return v;
}
__device__ __forceinline__ float waveReduceMax(float v) {
  for (int off = 32; off > 0; off >>= 1) v = fmaxf(v, __shfl_down(v, off, 64));
  return v;
}
__device__ __forceinline__ float siluf(float g) { return g / (1.f + expf(-g)); }
__device__ __forceinline__ unsigned short f2bf(float f) {
  union { float f; unsigned int u; } c; c.f = f;
  unsigned int u = c.u;
  return (unsigned short)((u + 0x7fffu + ((u >> 16) & 1u)) >> 16);
}

// ---------------------------------------------------------------- embed
__global__ __launch_bounds__(256) void k_embed(const int* __restrict__ ids,
                                               const float* __restrict__ embed,
                                               float* __restrict__ x) {
  int s = blockIdx.x;
  int id = ids[s];
  const float4* er = (const float4*)(embed + (size_t)id * DIM);
  float4* xr = (float4*)(x + (size_t)s * NSTR * DIM);
  for (int i = threadIdx.x; i < DIM / 4; i += 256) {
    float4 v = er[i];
    xr[i] = v; xr[i + 256] = v; xr[i + 512] = v; xr[i + 768] = v;
  }
}

// ------------------------------------------------- hyper-connection weights
template <int NOUT, bool SINK>
__global__ __launch_bounds__(256) void k_hc(const float* __restrict__ x,
                                            const float* __restrict__ W,
                                            const float* __restrict__ b,
                                            float* __restrict__ pre,
                                            float* __restrict__ post,
                                            float* __restrict__ Mout) {
  int s = blockIdx.x;
  int tid = threadIdx.x, lane = tid & 63, wid = tid >> 6;
  __shared__ __align__(16) float xs[NSTR * DIM];
  __shared__ float wred[4];
  __shared__ float wacc[4][NOUT];
  const float4* xr = (const float4*)(x + (size_t)s * NSTR * DIM);
  float ss = 0.f;
  for (int i = tid; i < NSTR * DIM / 4; i += 256) {
    float4 v = xr[i];
    ((float4*)xs)[i] = v;
    ss += v.x * v.x + v.y * v.y + v.z * v.z + v.w * v.w;
  }
  ss = waveReduceSum(ss);
  if (lane == 0) wred[wid] = ss;
  __syncthreads();
  float rstd = rsqrtf((wred[0] + wred[1] + wred[2] + wred[3]) / (float)(NSTR * DIM) + EPSV);
  float acc[NOUT];
#pragma unroll
  for (int j = 0; j < NOUT; j++) acc[j] = 0.f;
  for (int i = tid; i < NSTR * DIM; i += 256) {
    float xv = xs[i] * rstd;
    const float4* wr = (const float4*)(W + (size_t)i * NOUT);
#pragma unroll
    for (int j4 = 0; j4 < NOUT / 4; j4++) {
      float4 w = wr[j4];
      acc[j4 * 4 + 0] += xv * w.x; acc[j4 * 4 + 1] += xv * w.y;
      acc[j4 * 4 + 2] += xv * w.z; acc[j4 * 4 + 3] += xv * w.w;
    }
  }
#pragma unroll
  for (int j = 0; j < NOUT; j++) {
    float v = waveReduceSum(acc[j]);
    if (lane == 0) wacc[wid][j] = v;
  }
  __syncthreads();
  if (tid == 0) {
    float raw[NOUT];
#pragma unroll
    for (int j = 0; j < NOUT; j++)
      raw[j] = wacc[0][j] + wacc[1][j] + wacc[2][j] + wacc[3][j] + b[j];
    for (int n = 0; n < 4; n++) pre[s * 4 + n] = 1.f + tanhf(raw[n]);
    if (SINK) {
      for (int n = 0; n < 4; n++) post[s * 4 + n] = 1.f + tanhf(raw[4 + n]);
      float Mv[16];
      float mx = -1e30f;
      for (int i = 0; i < 16; i++) {
        float lg = raw[8 + i] + ((i % 5) == 0 ? 1.f : 0.f);  // + eye(4)
        Mv[i] = lg; mx = fmaxf(mx, lg);
      }
      for (int i = 0; i < 16; i++) Mv[i] = expf(Mv[i] - mx);
      for (int it = 0; it < 20; it++) {
        for (int n = 0; n < 4; n++) {
          float rs = Mv[n*4] + Mv[n*4+1] + Mv[n*4+2] + Mv[n*4+3] + EPSV;
          Mv[n*4] /= rs; Mv[n*4+1] /= rs; Mv[n*4+2] /= rs; Mv[n*4+3] /= rs;
        }
        for (int m = 0; m < 4; m++) {
          float cs = Mv[m] + Mv[4+m] + Mv[8+m] + Mv[12+m] + EPSV;
          Mv[m] /= cs; Mv[4+m] /= cs; Mv[8+m] /= cs; Mv[12+m] /= cs;
        }
      }
      for (int i = 0; i < 16; i++) Mout[s * 16 + i] = Mv[i];
    }
  }
}

// ------------------------------------------------- collapse + rms + scale
__global__ __launch_bounds__(256) void k_coll(const float* __restrict__ x,
                                              const float* __restrict__ pre,
                                              const float* __restrict__ g,
                                              float* __restrict__ out) {
  int s = blockIdx.x, tid = threadIdx.x, lane = tid & 63, wid = tid >> 6;
  __shared__ float cl[DIM];
  __shared__ float wred[4];
  float p0 = pre[s*4+0], p1 = pre[s*4+1], p2 = pre[s*4+2], p3 = pre[s*4+3];
  const float* xr = x + (size_t)s * NSTR * DIM;
  float ss = 0.f;
  for (int d = tid; d < DIM; d += 256) {
    float c = p0*xr[d] + p1*xr[DIM+d] + p2*xr[2*DIM+d] + p3*xr[3*DIM+d];
    cl[d] = c; ss += c * c;
  }
  ss = waveReduceSum(ss);
  if (lane == 0) wred[wid] = ss;
  __syncthreads();
  float rstd = rsqrtf((wred[0]+wred[1]+wred[2]+wred[3]) / (float)DIM + EPSV);
  for (int d = tid; d < DIM; d += 256)
    out[(size_t)s * DIM + d] = cl[d] * rstd * g[d];
}

// ---------------------------------------------------------------- sgemm
template <int BM, int BN>
__global__ __launch_bounds__(256) void sgemm(const float* __restrict__ A,
                                             const float* __restrict__ B,
                                             float* __restrict__ C,
                                             int M, int Kd, int Nn) {
  const int BK = 16;
  const int TM = BM / 16, TN = BN / 16;
  __shared__ __align__(16) float As[BK][BM + 4];
  __shared__ __align__(16) float Bs[BK][BN + 4];
  int tid = threadIdx.x;
  int bn = blockIdx.x, bm = blockIdx.y;
  int ty = tid >> 4, tx = tid & 15;
  float acc[TM][TN];
#pragma unroll
  for (int i = 0; i < TM; i++)
#pragma unroll
    for (int j = 0; j < TN; j++) acc[i][j] = 0.f;
  const float* Ab = A + (size_t)bm * BM * Kd;
  const float* Bb = B + (size_t)bn * BN;
  for (int k0 = 0; k0 < Kd; k0 += BK) {
    for (int i = tid; i < BM * BK / 4; i += 256) {
      int row = i >> 2, c4 = (i & 3) * 4;
      float4 v = *(const float4*)(Ab + (size_t)row * Kd + k0 + c4);
      As[c4+0][row] = v.x; As[c4+1][row] = v.y; As[c4+2][row] = v.z; As[c4+3][row] = v.w;
    }
    for (int i = tid; i < BK * BN / 4; i += 256) {
      int row = i / (BN / 4), c4 = (i % (BN / 4)) * 4;
      *(float4*)(&Bs[row][c4]) = *(const float4*)(Bb + (size_t)(k0 + row) * Nn + c4);
    }
    __syncthreads();
#pragma unroll
    for (int kk = 0; kk < BK; kk++) {
      float a[TM], b[TN];
#pragma unroll
      for (int i = 0; i < TM; i++) a[i] = As[kk][ty + i * 16];
#pragma unroll
      for (int j = 0; j < TN; j++) b[j] = Bs[kk][tx + j * 16];
#pragma unroll
      for (int i = 0; i < TM; i++)
#pragma unroll
        for (int j = 0; j < TN; j++) acc[i][j] += a[i] * b[j];
    }
    __syncthreads();
  }
  float* Cb = C + (size_t)(bm * BM) * Nn + bn * BN;
#pragma unroll
  for (int i = 0; i < TM; i++)
#pragma unroll
    for (int j = 0; j < TN; j++)
      Cb[(size_t)(ty + i * 16) * Nn + tx + j * 16] = acc[i][j];
}

// ---------------------------------------------------------------- rope
__global__ __launch_bounds__(256) void k_rope(float* __restrict__ Q, float* __restrict__ Kb) {
  int idx = blockIdx.x * 256 + threadIdx.x;   // s*256 + h*16 + j
  int s = idx >> 8;
  int r = idx & 255; int h = r >> 4; int j = r & 15;
  float inv = expf(-logf(10000.f) * (float)j / 16.f);
  float ang = (float)s * inv;
  float c = cosf(ang), sn = sinf(ang);
  size_t base = (size_t)s * DIM + h * HDIM;
  float x1 = Q[base + j], x2 = Q[base + 16 + j];
  Q[base + j] = x1 * c - x2 * sn; Q[base + 16 + j] = x1 * sn + x2 * c;
  x1 = Kb[base + j]; x2 = Kb[base + 16 + j];
  Kb[base + j] = x1 * c - x2 * sn; Kb[base + 16 + j] = x1 * sn + x2 * c;
}

// ------------------------------------------- flash attention (fp32, tiled)
// grid (16, NHEAD); block 512 = 16(ty) x 32(tx).
// Each block handles q-tiles {bi, 31-bi} (balanced: 33 k-tile steps total).
// Per q-tile: Qs[d][q] staged once (pre-scaled); per k-tile: Ks[d][k], Vs[k][d];
// online softmax (m,l per row); P staged transposed Ps[k][q] for PV.
__global__ __launch_bounds__(512) void k_fattn(const float* __restrict__ Q,
                                               const float* __restrict__ Kb,
                                               const float* __restrict__ V,
                                               float* __restrict__ O) {
  int bi = blockIdx.x, h = blockIdx.y;
  int tid = threadIdx.x;
  int ty = tid >> 5, tx = tid & 31;       // rows ty*4+i, cols tx*2+j
  __shared__ __align__(16) float Qs[64][68];
  __shared__ __align__(16) float Ks[64][68];
  __shared__ __align__(16) float Vs[64][68];
  __shared__ __align__(16) float Ps[64][68];
#pragma unroll 1
  for (int tile = 0; tile < 2; tile++) {
    int qt = tile ? (31 - bi) : bi;
    int q0 = qt * 64;
    __syncthreads();                      // previous tile's LDS reads done
    for (int idx = tid; idx < 1024; idx += 512) {
      int row = idx >> 4, c4 = (idx & 15) * 4;
      float4 v = *(const float4*)(Q + (size_t)(q0 + row) * DIM + h * HDIM + c4);
      Qs[c4+0][row] = v.x * 0.125f; Qs[c4+1][row] = v.y * 0.125f;
      Qs[c4+2][row] = v.z * 0.125f; Qs[c4+3][row] = v.w * 0.125f;
    }
    float m[4], l[4], acc_o[4][2];
#pragma unroll
    for (int i = 0; i < 4; i++) {
      m[i] = -1e30f; l[i] = 0.f; acc_o[i][0] = 0.f; acc_o[i][1] = 0.f;
    }
#pragma unroll 1
    for (int kt = 0; kt <= qt; kt++) {
      int k0 = kt * 64;
      __syncthreads();                    // prev PV reads + Qs stage visible
      for (int idx = tid; idx < 1024; idx += 512) {
        int row = idx >> 4, c4 = (idx & 15) * 4;
        float4 kv = *(const float4*)(Kb + (size_t)(k0 + row) * DIM + h * HDIM + c4);
        Ks[c4+0][row] = kv.x; Ks[c4+1][row] = kv.y;
        Ks[c4+2][row] = kv.z; Ks[c4+3][row] = kv.w;
        float4 vv = *(const float4*)(V + (size_t)(k0 + row) * DIM + h * HDIM + c4);
        *(float4*)(&Vs[row][c4]) = vv;
      }
      __syncthreads();
      float acc[4][2];
#pragma unroll
      for (int i = 0; i < 4; i++) { acc[i][0] = 0.f; acc[i][1] = 0.f; }
#pragma unroll 4
      for (int dd = 0; dd < 64; dd++) {
        float4 a = *(const float4*)(&Qs[dd][ty * 4]);
        float2 b = *(const float2*)(&Ks[dd][tx * 2]);
        acc[0][0] += a.x * b.x; acc[0][1] += a.x * b.y;
        acc[1][0] += a.y * b.x; acc[1][1] += a.y * b.y;
        acc[2][0] += a.z * b.x; acc[2][1] += a.z * b.y;
        acc[3][0] += a.w * b.x; acc[3][1] += a.w * b.y;
      }
      if (kt == qt) {                     // causal mask on diagonal tile
#pragma unroll
        for (int i = 0; i < 4; i++)
#pragma unroll
          for (int j = 0; j < 2; j++)
            if (k0 + tx * 2 + j > q0 + ty * 4 + i) acc[i][j] = -1e30f;
      }
      float tm[4], p[4][2], rs[4];
#pragma unroll
      for (int i = 0; i < 4; i++) tm[i] = fmaxf(acc[i][0], acc[i][1]);
#pragma unroll
      for (int sh = 1; sh < 32; sh <<= 1)
#pragma unroll
        for (int i = 0; i < 4; i++) tm[i] = fmaxf(tm[i], __shfl_xor(tm[i], sh, 64));
#pragma unroll
      for (int i = 0; i < 4; i++) {
        float mn = fmaxf(m[i], tm[i]);
        float c = expf(m[i] - mn);
        m[i] = mn;
        l[i] *= c; acc_o[i][0] *= c; acc_o[i][1] *= c;
        p[i][0] = expf(acc[i][0] - mn);
        p[i][1] = expf(acc[i][1] - mn);
        rs[i] = p[i][0] + p[i][1];
      }
#pragma unroll
      for (int sh = 1; sh < 32; sh <<= 1)
#pragma unroll
        for (int i = 0; i < 4; i++) rs[i] += __shfl_xor(rs[i], sh, 64);
#pragma unroll
      for (int i = 0; i < 4; i++) l[i] += rs[i];
      // stage P transposed: Ps[k][q]
      float4 pc0 = {p[0][0], p[1][0], p[2][0], p[3][0]};
      float4 pc1 = {p[0][1], p[1][1], p[2][1], p[3][1]};
      *(float4*)(&Ps[tx * 2 + 0][ty * 4]) = pc0;
      *(float4*)(&Ps[tx * 2 + 1][ty * 4]) = pc1;
      __syncthreads();
#pragma unroll 4
      for (int kk = 0; kk < 64; kk++) {
        float4 pa = *(const float4*)(&Ps[kk][ty * 4]);
        float2 bv = *(const float2*)(&Vs[kk][tx * 2]);
        acc_o[0][0] += pa.x * bv.x; acc_o[0][1] += pa.x * bv.y;
        acc_o[1][0] += pa.y * bv.x; acc_o[1][1] += pa.y * bv.y;
        acc_o[2][0] += pa.z * bv.x; acc_o[2][1] += pa.z * bv.y;
        acc_o[3][0] += pa.w * bv.x; acc_o[3][1] += pa.w * bv.y;
      }
    }
#pragma unroll
    for (int i = 0; i < 4; i++) {
      float inv = 1.f / l[i];
      float2 ov = {acc_o[i][0] * inv, acc_o[i][1] * inv};
      *(float2*)(O + (size_t)(q0 + ty * 4 + i) * DIM + h * HDIM + tx * 2) = ov;
    }
  }
}

// --------------------------------------------- hyper-connection update
__global__ __launch_bounds__(256) void k_hcupd(const float* __restrict__ x,
                                               const float* __restrict__ a,
                                               const float* __restrict__ a2,
                                               const float* __restrict__ post,
                                               const float* __restrict__ Mb,
                                               float* __restrict__ xo) {
  int s = blockIdx.x, tid = threadIdx.x;
  __shared__ float Ms[16];
  if (tid < 16) Ms[tid] = Mb[s * 16 + tid];
  __syncthreads();
  float p0 = post[s*4+0], p1 = post[s*4+1], p2 = post[s*4+2], p3 = post[s*4+3];
  const float* xr = x + (size_t)s * NSTR * DIM;
  float* xw = xo + (size_t)s * NSTR * DIM;
  for (int d = tid; d < DIM; d += 256) {
    float av = a[(size_t)s * DIM + d];
    if (a2) av += a2[(size_t)s * DIM + d];
    float x0 = xr[d], x1 = xr[DIM+d], x2 = xr[2*DIM+d], x3 = xr[3*DIM+d];
    float o0 = p0*av + Ms[0]*x0 + Ms[4]*x1 + Ms[8]*x2  + Ms[12]*x3;
    float o1 = p1*av + Ms[1]*x0 + Ms[5]*x1 + Ms[9]*x2  + Ms[13]*x3;
    float o2 = p2*av + Ms[2]*x0 + Ms[6]*x1 + Ms[10]*x2 + Ms[14]*x3;
    float o3 = p3*av + Ms[3]*x0 + Ms[7]*x1 + Ms[11]*x2 + Ms[15]*x3;
    xw[d] = o0; xw[DIM+d] = o1; xw[2*DIM+d] = o2; xw[3*DIM+d] = o3;
  }
}

// ---------------------------------------------------------------- gating
__global__ __launch_bounds__(256) void k_gate(const float* __restrict__ hb,
                                              const float* __restrict__ gw,
                                              float* __restrict__ gates) {
  int t = blockIdx.x, tid = threadIdx.x;
  int e = tid >> 5, l32 = tid & 31;
  __shared__ float ge[8];
  const float* xr = hb + (size_t)t * DIM;
  const float* wr = gw + (size_t)e * DIM;
  float a = 0.f;
  for (int d = l32; d < DIM; d += 32) a += xr[d] * wr[d];
  for (int off = 16; off > 0; off >>= 1) a += __shfl_down(a, off, 32);
  if (l32 == 0) ge[e] = a;
  __syncthreads();
  if (tid < 8) {
    float v = ge[tid];
    float sp = fmaxf(v, 0.f) + log1pf(expf(-fabsf(v)));  // softplus, stable
    gates[t * 8 + tid] = sqrtf(sp);
  }
}

__global__ __launch_bounds__(256) void k_route(const float* __restrict__ gates,
                                               const int* __restrict__ ids,
                                               const int* __restrict__ tid2eid,
                                               int is_hash,
                                               int* __restrict__ idxb,
                                               float* __restrict__ wgtb) {
  int t = blockIdx.x * 256 + threadIdx.x;
  if (t >= S_LEN) return;
  int e0, e1;
  if (is_hash) {
    int id = ids[t];
    e0 = tid2eid[id * 2]; e1 = tid2eid[id * 2 + 1];
  } else {
    const float* g = gates + t * 8;
    e0 = 0; float b0 = g[0];
    for (int e = 1; e < 8; e++) if (g[e] > b0) { b0 = g[e]; e0 = e; }
    e1 = (e0 == 0) ? 1 : 0; float b1 = g[e1];
    for (int e = 0; e < 8; e++) {
      if (e == e0) continue;
      if (g[e] > b1) { b1 = g[e]; e1 = e; }
    }
  }
  float w0 = gates[t * 8 + e0], w1 = gates[t * 8 + e1];
  float f = 2.5f / (w0 + w1 + 1e-20f);
  idxb[t * 2] = e0; idxb[t * 2 + 1] = e1;
  wgtb[t * 2] = w0 * f; wgtb[t * 2 + 1] = w1 * f;
}

// --------------------------------------------- MoE plan: group rows by expert
__global__ __launch_bounds__(1024) void k_moe_plan(const int* __restrict__ idxb,
                                                   int* __restrict__ plan) {
  __shared__ int scnt[NEXP], soff[NEXP], sfill[NEXP];
  int tid = threadIdx.x;
  if (tid < NEXP) { scnt[tid] = 0; sfill[tid] = 0; }
  __syncthreads();
  for (int r = tid; r < 2 * S_LEN; r += 1024) atomicAdd(&scnt[idxb[r]], 1);
  __syncthreads();
  if (tid == 0) {
    int nt = 0, run = 0;
    for (int e = 0; e < NEXP; e++) {
      soff[e] = run;
      int c = scnt[e];
      for (int t0 = 0; t0 < c; t0 += 64) {
        plan[PLAN_TILES + nt * 4 + 0] = e;
        plan[PLAN_TILES + nt * 4 + 1] = run + t0;   // row0
        plan[PLAN_TILES + nt * 4 + 2] = run + c;    // rowEnd (expert range end)
        nt++;
      }
      run += c;
    }
    plan[0] = nt;
  }
  __syncthreads();
  for (int r = tid; r < 2 * S_LEN; r += 1024) {
    int e = idxb[r];
    int pos = soff[e] + atomicAdd(&sfill[e], 1);
    plan[PLAN_R2T + pos] = r;     // grouped row -> (token,slot)
    plan[PLAN_RPOS + r] = pos;    // (token,slot) -> grouped row
  }
}

// --------------------------------------------- grouped expert g/u GEMM
__global__ __launch_bounds__(256) void k_moe_gu(const float* __restrict__ hb,
                                                const int* __restrict__ plan,
                                                const float* __restrict__ wg,
                                                const float* __restrict__ wu,
                                                float* __restrict__ act) {
  int tl = blockIdx.y;
  if (tl >= plan[0]) return;
  const int* td = plan + PLAN_TILES + tl * 4;
  int e = td[0], row0 = td[1], rowEnd = td[2];
  int bn = blockIdx.x;                        // 64-col tile over FF
  const int* r2t = plan + PLAN_R2T;
  __shared__ int toks[64];
  __shared__ __align__(16) float As[16][68];
  __shared__ __align__(16) float Bg[16][68];
  __shared__ __align__(16) float Bu[16][68];
  int tid = threadIdx.x;
  if (tid < 64) {
    int gr = row0 + tid;
    toks[tid] = r2t[min(gr, rowEnd - 1)] >> 1;
  }
  __syncthreads();
  int ty = tid >> 4, tx = tid & 15;
  float accg[4][4], accu[4][4];
#pragma unroll
  for (int i = 0; i < 4; i++)
#pragma unroll
    for (int j = 0; j < 4; j++) { accg[i][j] = 0.f; accu[i][j] = 0.f; }
  const float* wgb = wg + (size_t)e * DIM * FF + bn * 64;
  const float* wub = wu + (size_t)e * DIM * FF + bn * 64;
  int arow = tid >> 2, ac4 = (tid & 3) * 4;   // A: 64 rows x 4 float4
  int brow = tid >> 4, bc4 = (tid & 15) * 4;  // B: 16 rows x 16 float4
  for (int k0 = 0; k0 < DIM; k0 += 16) {
    float4 av = *(const float4*)(hb + (size_t)toks[arow] * DIM + k0 + ac4);
    float4 gv = *(const float4*)(wgb + (size_t)(k0 + brow) * FF + bc4);
    float4 uv = *(const float4*)(wub + (size_t)(k0 + brow) * FF + bc4);
    __syncthreads();
    As[ac4+0][arow] = av.x; As[ac4+1][arow] = av.y;
    As[ac4+2][arow] = av.z; As[ac4+3][arow] = av.w;
    *(float4*)(&Bg[brow][bc4]) = gv;
    *(float4*)(&Bu[brow][bc4]) = uv;
    __syncthreads();
#pragma unroll
    for (int kk = 0; kk < 16; kk++) {
      float a[4], bgv[4], buv[4];
#pragma unroll
      for (int i = 0; i < 4; i++) a[i] = As[kk][ty + i * 16];
#pragma unroll
      for (int j = 0; j < 4; j++) { bgv[j] = Bg[kk][tx + j * 16]; buv[j] = Bu[kk][tx + j * 16]; }
#pragma unroll
      for (int i = 0; i < 4; i++)
#pragma unroll
        for (int j = 0; j < 4; j++) {
          accg[i][j] += a[i] * bgv[j];
          accu[i][j] += a[i] * buv[j];
        }
    }
  }
#pragma unroll
  for (int i = 0; i < 4; i++) {
    int gr = row0 + ty + i * 16;
    if (gr < rowEnd) {
#pragma unroll
      for (int j = 0; j < 4; j++)
        act[(size_t)gr * FF + bn * 64 + tx + j * 16] = siluf(accg[i][j]) * accu[i][j];
    }
  }
}

// --------------------------------------------- grouped expert down GEMM
__global__ __launch_bounds__(256) void k_moe_down(const float* __restrict__ act,
                                                  const int* __restrict__ plan,
                                                  const float* __restrict__ wd,
                                                  float* __restrict__ rowout) {
  int tl = blockIdx.y;
  if (tl >= plan[0]) return;
  const int* td = plan + PLAN_TILES + tl * 4;
  int e = td[0], row0 = td[1], rowEnd = td[2];
  int bn = blockIdx.x;                        // 64-col tile over DIM
  __shared__ __align__(16) float As[16][68];
  __shared__ __align__(16) float Bs[16][68];
  int tid = threadIdx.x;
  int ty = tid >> 4, tx = tid & 15;
  float acc[4][4];
#pragma unroll
  for (int i = 0; i < 4; i++)
#pragma unroll
    for (int j = 0; j < 4; j++) acc[i][j] = 0.f;
  const float* wdb = wd + (size_t)e * FF * DIM + bn * 64;
  int arow = tid >> 2, ac4 = (tid & 3) * 4;
  int brow = tid >> 4, bc4 = (tid & 15) * 4;
  int asrc = min(row0 + arow, rowEnd - 1);
  for (int k0 = 0; k0 < FF; k0 += 16) {
    float4 av = *(const float4*)(act + (size_t)asrc * FF + k0 + ac4);
    float4 bv = *(const float4*)(wdb + (size_t)(k0 + brow) * DIM + bc4);
    __syncthreads();
    As[ac4+0][arow] = av.x; As[ac4+1][arow] = av.y;
    As[ac4+2][arow] = av.z; As[ac4+3][arow] = av.w;
    *(float4*)(&Bs[brow][bc4]) = bv;
    __syncthreads();
#pragma unroll
    for (int kk = 0; kk < 16; kk++) {
      float a[4], b[4];
#pragma unroll
      for (int i = 0; i < 4; i++) a[i] = As[kk][ty + i * 16];
#pragma unroll
      for (int j = 0; j < 4; j++) b[j] = Bs[kk][tx + j * 16];
#pragma unroll
      for (int i = 0; i < 4; i++)
#pragma unroll
        for (int j = 0; j < 4; j++) acc[i][j] += a[i] * b[j];
    }
  }
#pragma unroll
  for (int i = 0; i < 4; i++) {
    int gr = row0 + ty + i * 16;
    if (gr < rowEnd) {
#pragma unroll
      for (int j = 0; j < 4; j++)
        rowout[(size_t)gr * DIM + bn * 64 + tx + j * 16] = acc[i][j];
    }
  }
}

// --------------------------------------------- combine the two slots
__global__ __launch_bounds__(256) void k_moe_comb(const float* __restrict__ rowout,
                                                  const int* __restrict__ plan,
                                                  const float* __restrict__ wgtb,
                                                  float* __restrict__ routed) {
  int t = blockIdx.x, tid = threadIdx.x;
  const int* rowpos = plan + PLAN_RPOS;
  int p0 = rowpos[t * 2], p1 = rowpos[t * 2 + 1];
  float w0 = wgtb[t * 2], w1 = wgtb[t * 2 + 1];
  const float4* r0 = (const float4*)(rowout + (size_t)p0 * DIM);
  const float4* r1 = (const float4*)(rowout + (size_t)p1 * DIM);
  float4* o = (float4*)(routed + (size_t)t * DIM);
  float4 a = r0[tid], b = r1[tid], c;
  c.x = w0 * a.x + w1 * b.x; c.y = w0 * a.y + w1 * b.y;
  c.z = w0 * a.z + w1 * b.z; c.w = w0 * a.w + w1 * b.w;
  o[tid] = c;
}

__global__ __launch_bounds__(256) void k_silu_mul(const float* __restrict__ g,
                                                  const float* __restrict__ u,
                                                  float* __restrict__ o, int n) {
  int i = blockIdx.x * 256 + threadIdx.x;
  if (i < n) { float gv = g[i]; o[i] = siluf(gv) * u[i]; }
}

// --------------------------------------------- lm_head bf16 MFMA path
__global__ __launch_bounds__(256) void k_castA(const float* __restrict__ in,
                                               short* __restrict__ out) {
  int i = blockIdx.x * 256 + threadIdx.x;     // over 2M/4
  float4 v = ((const float4*)in)[i];
  short4 o;
  o.x = (short)f2bf(v.x); o.y = (short)f2bf(v.y);
  o.z = (short)f2bf(v.z); o.w = (short)f2bf(v.w);
  ((short4*)out)[i] = o;
}

// transpose-cast chunk of lm_head: B f32 [1024][32000] cols [c0,c0+LM_CHUNK)
// -> BT bf16 [LM_CHUNK][1024]
__global__ __launch_bounds__(256) void k_castT(const float* __restrict__ B,
                                               short* __restrict__ BT, int c0) {
  __shared__ short tile[32][34];
  int bx = blockIdx.x, by = blockIdx.y;       // n-tile (chunk-local), k-tile
  int t = threadIdx.x;
  int n0 = c0 + bx * 32, k0 = by * 32;
  int r = t >> 3, nq = (t & 7) * 4;
  float4 v = *(const float4*)(B + (size_t)(k0 + r) * VOC + n0 + nq);
  tile[nq + 0][r] = (short)f2bf(v.x);
  tile[nq + 1][r] = (short)f2bf(v.y);
  tile[nq + 2][r] = (short)f2bf(v.z);
  tile[nq + 3][r] = (short)f2bf(v.w);
  __syncthreads();
  int n = t >> 3, kq = (t & 7) * 4;
  short4 o;
  o.x = tile[n][kq + 0]; o.y = tile[n][kq + 1];
  o.z = tile[n][kq + 2]; o.w = tile[n][kq + 3];
  *(short4*)(BT + (size_t)(bx * 32 + n) * 1024 + k0 + kq) = o;
}

// C[M, c0..c0+LM_CHUNK) = A(bf16 [2048][1024]) @ BT(bf16 [LM_CHUNK][1024])^T
__global__ __launch_bounds__(256) void k_lmgemm(const short* __restrict__ A,
                                                const short* __restrict__ BT,
                                                float* __restrict__ C, int c0) {
  __shared__ __align__(16) short As[128 * 40];  // row stride 40 shorts = 80B
  __shared__ __align__(16) short Bs[128 * 40];
  int t = threadIdx.x;
  int bn = blockIdx.x, bm = blockIdx.y;
  int w = t >> 6, l = t & 63;
  int wr = w >> 1, wc = w & 1;
  f32x4 acc[4][4];
#pragma unroll
  for (int i = 0; i < 4; i++)
#pragma unroll
    for (int j = 0; j < 4; j++) acc[i][j] = (f32x4){0.f, 0.f, 0.f, 0.f};
  int srow = t >> 1, sseg = t & 1;
  const short* Ag = A + (size_t)(bm * 128 + srow) * 1024 + sseg * 16;
  const short* Bg = BT + (size_t)(bn * 128 + srow) * 1024 + sseg * 16;
  short* Asw = As + srow * 40 + sseg * 16;
  short* Bsw = Bs + srow * 40 + sseg * 16;
  const short* Ar = As + (wr * 64 + (l & 15)) * 40 + (l >> 4) * 8;
  const short* Br = Bs + (wc * 64 + (l & 15)) * 40 + (l >> 4) * 8;
  for (int k0 = 0; k0 < 1024; k0 += 32) {
    s16x8 a0 = *(const s16x8*)(Ag + k0);
    s16x8 a1 = *(const s16x8*)(Ag + k0 + 8);
    s16x8 b0 = *(const s16x8*)(Bg + k0);
    s16x8 b1 = *(const s16x8*)(Bg + k0 + 8);
    __syncthreads();
    *(s16x8*)(Asw) = a0; *(s16x8*)(Asw + 8) = a1;
    *(s16x8*)(Bsw) = b0; *(s16x8*)(Bsw + 8) = b1;
    __syncthreads();
    s16x8 af[4], bf[4];
#pragma unroll
    for (int i = 0; i < 4; i++) af[i] = *(const s16x8*)(Ar + i * 640);
#pragma unroll
    for (int j = 0; j < 4; j++) bf[j] = *(const s16x8*)(Br + j * 640);
#pragma unroll
    for (int i = 0; i < 4; i++)
#pragma unroll
      for (int j = 0; j < 4; j++)
        acc[i][j] = __builtin_amdgcn_mfma_f32_16x16x32_bf16(af[i], bf[j], acc[i][j], 0, 0, 0);
  }
  int rq = (l >> 4) * 4, cn = l & 15;
#pragma unroll
  for (int i = 0; i < 4; i++)
#pragma unroll
    for (int j = 0; j < 4; j++) {
      float* Cp = C + (size_t)(bm * 128 + wr * 64 + i * 16 + rq) * VOC
                  + c0 + bn * 128 + wc * 64 + j * 16 + cn;
#pragma unroll
      for (int r = 0; r < 4; r++) Cp[(size_t)r * VOC] = acc[i][j][r];
    }
}

// =======================================================================
extern "C" void kernel_launch(void* const* d_in, const int* in_sizes, int n_in,
                              void* d_out, int out_size, void* d_ws, size_t ws_size,
                              hipStream_t stream) {
  (void)in_sizes; (void)n_in; (void)out_size; (void)ws_size;
  const int*   ids      = (const int*)d_in[0];
  const int*   tid2eid  = (const int*)d_in[1];
  const float* embed    = (const float*)d_in[2];
  const float* attn_hc_w= (const float*)d_in[3];
  const float* attn_hc_b= (const float*)d_in[4];
  const float* ffn_hc_w = (const float*)d_in[5];
  const float* ffn_hc_b = (const float*)d_in[6];
  const float* ln1      = (const float*)d_in[7];
  const float* ln2      = (const float*)d_in[8];
  const float* wq       = (const float*)d_in[9];
  const float* wk       = (const float*)d_in[10];
  const float* wv       = (const float*)d_in[11];
  const float* wo       = (const float*)d_in[12];
  const float* gate_w   = (const float*)d_in[13];
  const float* wg_e     = (const float*)d_in[14];
  const float* wu_e     = (const float*)d_in[15];
  const float* wd_e     = (const float*)d_in[16];
  const float* wg_s     = (const float*)d_in[17];
  const float* wu_s     = (const float*)d_in[18];
  const float* wd_s     = (const float*)d_in[19];
  const float* head_w   = (const float*)d_in[20];
  const float* head_b   = (const float*)d_in[21];
  const float* fnw      = (const float*)d_in[22];
  const float* lm_head  = (const float*)d_in[23];
  float* out = (float*)d_out;

  float* ws = (float*)d_ws;
  size_t o = 0;
  float* X    = ws + o; o += (size_t)S_LEN * NSTR * DIM;   // state, updated in place
  float* HBUF = ws + o; o += (size_t)S_LEN * DIM;
  float* T1   = ws + o; o += (size_t)S_LEN * DIM;          // q / expert act / ABF16
  float* T2   = ws + o; o += (size_t)S_LEN * DIM;          // k / routed / BT16 lo
  float* T3   = ws + o; o += (size_t)S_LEN * DIM;          // v / gs,acts / BT16 hi
  float* T4   = ws + o; o += (size_t)S_LEN * DIM;          // o / us,shared
  float* PRE  = ws + o; o += (size_t)S_LEN * 4;
  float* POST = ws + o; o += (size_t)S_LEN * 4;
  float* MM   = ws + o; o += (size_t)S_LEN * 16;
  float* GATES= ws + o; o += (size_t)S_LEN * 8;
  float* WGT  = ws + o; o += (size_t)S_LEN * 2;
  int*   IDX  = (int*)(ws + o); o += (size_t)S_LEN * 2;
  int*   PLAN = (int*)(ws + o); o += (size_t)PLAN_INTS;
  // rowout (4096 x 1024 f32 = 16.8 MB) lives in d_out scratch space; it is
  // fully dead before the final lm_head GEMM overwrites all of d_out.
  float* ROWOUT = out;
  // final-head scratch (T1..T4 are dead by then):
  short* ABF16 = (short*)T1;                  // 2048x1024 bf16 = 4 MB (T1 = 8 MB)
  short* BT16  = (short*)T2;                  // LM_CHUNK x 1024 bf16 = 13.1 MB (T2+T3)

  dim3 g128(DIM / 128, S_LEN / 128);
  dim3 gattn(16, NHEAD);

  k_embed<<<S_LEN, 256, 0, stream>>>(ids, embed, X);

  for (int l = 0; l < 2; l++) {
    // ---- attention sub-block
    k_hc<NCC, true><<<S_LEN, 256, 0, stream>>>(X, attn_hc_w + (size_t)l * NSTR * DIM * NCC,
                                               attn_hc_b + l * NCC, PRE, POST, MM);
    k_coll<<<S_LEN, 256, 0, stream>>>(X, PRE, ln1 + (size_t)l * DIM, HBUF);
    sgemm<128,128><<<g128, 256, 0, stream>>>(HBUF, wq + (size_t)l * DIM * DIM, T1, S_LEN, DIM, DIM);
    sgemm<128,128><<<g128, 256, 0, stream>>>(HBUF, wk + (size_t)l * DIM * DIM, T2, S_LEN, DIM, DIM);
    sgemm<128,128><<<g128, 256, 0, stream>>>(HBUF, wv + (size_t)l * DIM * DIM, T3, S_LEN, DIM, DIM);
    k_rope<<<S_LEN, 256, 0, stream>>>(T1, T2);
    k_fattn<<<gattn, 512, 0, stream>>>(T1, T2, T3, T4);
    sgemm<128,128><<<g128, 256, 0, stream>>>(T4, wo + (size_t)l * DIM * DIM, HBUF, S_LEN, DIM, DIM);
    k_hcupd<<<S_LEN, 256, 0, stream>>>(X, HBUF, nullptr, POST, MM, X);

    // ---- MoE sub-block (grouped-by-expert GEMMs)
    k_hc<NCC, true><<<S_LEN, 256, 0, stream>>>(X, ffn_hc_w + (size_t)l * NSTR * DIM * NCC,
                                               ffn_hc_b + l * NCC, PRE, POST, MM);
    k_coll<<<S_LEN, 256, 0, stream>>>(X, PRE, ln2 + (size_t)l * DIM, HBUF);
    k_gate<<<S_LEN, 256, 0, stream>>>(HBUF, gate_w + (size_t)l * NEXP * DIM, GATES);
    k_route<<<S_LEN / 256, 256, 0, stream>>>(GATES, ids, tid2eid, (l == 0) ? 1 : 0, IDX, WGT);
    k_moe_plan<<<1, 1024, 0, stream>>>(IDX, PLAN);
    k_moe_gu<<<dim3(FF / 64, MAX_TILES), 256, 0, stream>>>(HBUF, PLAN,
                                               wg_e + (size_t)l * NEXP * DIM * FF,
                                               wu_e + (size_t)l * NEXP * DIM * FF, T1);
    k_moe_down<<<dim3(DIM / 64, MAX_TILES), 256, 0, stream>>>(T1, PLAN,
                                               wd_e + (size_t)l * NEXP * FF * DIM, ROWOUT);
    k_moe_comb<<<S_LEN, 256, 0, stream>>>(ROWOUT, PLAN, WGT, T2);
    dim3 g64a(FF / 64, S_LEN / 64);
    sgemm<64,64><<<g64a, 256, 0, stream>>>(HBUF, wg_s + (size_t)l * DIM * FF, T3, S_LEN, DIM, FF);
    sgemm<64,64><<<g64a, 256, 0, stream>>>(HBUF, wu_s + (size_t)l * DIM * FF, T4, S_LEN, DIM, FF);
    k_silu_mul<<<(S_LEN * FF) / 256, 256, 0, stream>>>(T3, T4, T3, S_LEN * FF);
    dim3 g64b(DIM / 64, S_LEN / 64);
    sgemm<64,64><<<g64b, 256, 0, stream>>>(T3, wd_s + (size_t)l * FF * DIM, T4, S_LEN, FF, DIM);
    k_hcupd<<<S_LEN, 256, 0, stream>>>(X, T2, T4, POST, MM, X);
  }

  // ---- final head (bf16 MFMA lm_head)
  k_hc<4, false><<<S_LEN, 256, 0, stream>>>(X, head_w, head_b, PRE, nullptr, nullptr);
  k_coll<<<S_LEN, 256, 0, stream>>>(X, PRE, fnw, HBUF);
  k_castA<<<(S_LEN * DIM / 4) / 256, 256, 0, stream>>>(HBUF, ABF16);
  for (int c = 0; c < VOC / LM_CHUNK; c++) {
    k_castT<<<dim3(LM_CHUNK / 32, DIM / 32), 256, 0, stream>>>(lm_head, BT16, c * LM_CHUNK);
    k_lmgemm<<<dim3(LM_CHUNK / 128, S_LEN / 128), 256, 0, stream>>>(ABF16, BT16, out, c * LM_CHUNK);
  }
}